// Round 4
// baseline (1291.309 us; speedup 1.0000x reference)
//
#include <hip/hip_runtime.h>
#include <cstdint>
#include <cstddef>

#define N_LAYER 4
#define VOCABSZ 50280
#define VOCABPAD 50304
#define DMODEL 768
#define DINNER 1536
#define DSTATE 16
#define DTRANK 48
#define SEQL 1024

typedef __bf16 bf16x8 __attribute__((ext_vector_type(8)));
typedef unsigned short us8 __attribute__((ext_vector_type(8)));
typedef float f32x4 __attribute__((ext_vector_type(4)));

__device__ __forceinline__ unsigned short f2bf(float f) {
    unsigned int u = __builtin_bit_cast(unsigned int, f);
    u = (u + 0x7FFFu + ((u >> 16) & 1u)) >> 16;   // round-to-nearest-even
    return (unsigned short)u;
}

__device__ __forceinline__ void glds16(const unsigned short* g, unsigned short* l) {
    __builtin_amdgcn_global_load_lds(
        (const __attribute__((address_space(1))) void*)g,
        (__attribute__((address_space(3))) void*)l, 16, 0, 0);
}

// ---------------------------------------------------------------------------
// fp32 -> bf16 bulk convert (8 elems/thread)
// ---------------------------------------------------------------------------
__global__ __launch_bounds__(256) void cvt_bf16_kernel(
    const float* __restrict__ src, unsigned short* __restrict__ dst, int n8)
{
    int i = blockIdx.x * 256 + threadIdx.x;
    if (i >= n8) return;
    const float4* s = (const float4*)src + (size_t)i * 2;
    float4 a = s[0], b = s[1];
    us8 o = { f2bf(a.x), f2bf(a.y), f2bf(a.z), f2bf(a.w),
              f2bf(b.x), f2bf(b.y), f2bf(b.z), f2bf(b.w) };
    *(us8*)(dst + (size_t)i * 8) = o;
}

// ---------------------------------------------------------------------------
// x_proj_w (N_LAYER,80,1536) fp32 -> bf16, padded to 128 rows/layer (rows>=80
// zeroed so the 128-row GEMM staging reads defined data). 8 cols/thread.
// ---------------------------------------------------------------------------
__global__ __launch_bounds__(256) void cvt_xw_kernel(
    const float* __restrict__ xw, unsigned short* __restrict__ xwB)
{
    int g = blockIdx.x * 256 + threadIdx.x;
    if (g >= N_LAYER * 128 * 192) return;
    int row = g / 192;              // padded row 0 .. 4*128-1
    int c8  = g % 192;
    int layer = row >> 7;
    int r = row & 127;
    us8 o;
    if (r < 80) {
        const float4* s = (const float4*)(xw + ((size_t)(layer * 80 + r) * DINNER) + c8 * 8);
        float4 a = s[0], b = s[1];
        o = (us8){ f2bf(a.x), f2bf(a.y), f2bf(a.z), f2bf(a.w),
                   f2bf(b.x), f2bf(b.y), f2bf(b.z), f2bf(b.w) };
    } else {
        o = (us8){0, 0, 0, 0, 0, 0, 0, 0};
    }
    *(us8*)(xwB + (size_t)row * DINNER + c8 * 8) = o;
}

// ---------------------------------------------------------------------------
// bf16 NT GEMM, m97 structure: C[m,n] = sum_k A[m,k]*B[n,k] (+ADDSRC)
// A: 1024 x K bf16, B: N(padded to >=128-row tiles) x K bf16. 128x128 tile,
// BK=32, 4 waves. Staging via global_load_lds width=16 (all async, ONE drain
// per K-iter -- the round-2 reg-staged variant exposed two latencies/iter
// and regressed 167->205 us). XCD-bijective swizzle (T1): the 8 M-blocks
// sharing a B-panel land on one XCD (grid%8==0 for all users: 192/48/8/3144);
// measured FETCH 307->108 MB on logits.
// ---------------------------------------------------------------------------
template <int ADD>
__device__ __forceinline__ void gemm_bf_body(
    const unsigned short* __restrict__ A, const unsigned short* __restrict__ B,
    const float* __restrict__ ADDSRC, float* __restrict__ C, int N, int K)
{
    __shared__ unsigned short sA[128 * 32];
    __shared__ unsigned short sB[128 * 32];

    const int tid  = threadIdx.x;
    const int lane = tid & 63;
    const int wave = tid >> 6;
    const int wm = (wave & 1) * 64;
    const int wn = (wave >> 1) * 64;
    const int bid = blockIdx.x;
    const int cpx = (int)gridDim.x >> 3;
    const int swz = (bid & 7) * cpx + (bid >> 3);
    const int bm = (swz & 7) << 7;
    const int bn = (swz >> 3) << 7;

    const unsigned short* Ag0 = A + (size_t)(bm + (tid >> 2)) * K + (tid & 3) * 8;
    const unsigned short* Ag1 = Ag0 + (size_t)64 * K;
    const unsigned short* Bg0 = B + (size_t)(bn + (tid >> 2)) * K + (tid & 3) * 8;
    const unsigned short* Bg1 = Bg0 + (size_t)64 * K;
    unsigned short* lA0 = sA + tid * 8;
    unsigned short* lA1 = lA0 + 2048;
    unsigned short* lB0 = sB + tid * 8;
    unsigned short* lB1 = lB0 + 2048;

    f32x4 acc[4][4];
#pragma unroll
    for (int i = 0; i < 4; ++i)
#pragma unroll
        for (int j = 0; j < 4; ++j) acc[i][j] = (f32x4){0.f, 0.f, 0.f, 0.f};

    const int fr = (lane & 15) * 32 + (lane >> 4) * 8;

    for (int k0 = 0; k0 < K; k0 += 32) {
        __syncthreads();                       // prev tile fully consumed
        glds16(Ag0, lA0);
        glds16(Ag1, lA1);
        glds16(Bg0, lB0);
        glds16(Bg1, lB1);
        Ag0 += 32; Ag1 += 32; Bg0 += 32; Bg1 += 32;
        __syncthreads();                       // vmcnt(0) drain -> tile ready

        bf16x8 af[4], bfr[4];
#pragma unroll
        for (int t = 0; t < 4; ++t) {
            af[t]  = __builtin_bit_cast(bf16x8, *(const us8*)&sA[(wm + t * 16) * 32 + fr]);
            bfr[t] = __builtin_bit_cast(bf16x8, *(const us8*)&sB[(wn + t * 16) * 32 + fr]);
        }
#pragma unroll
        for (int mt = 0; mt < 4; ++mt)
#pragma unroll
            for (int nt = 0; nt < 4; ++nt)
                acc[mt][nt] = __builtin_amdgcn_mfma_f32_16x16x32_bf16(
                    af[mt], bfr[nt], acc[mt][nt], 0, 0, 0);
    }

    const int cn = lane & 15;
    const int cm = (lane >> 4) * 4;
#pragma unroll
    for (int mt = 0; mt < 4; ++mt) {
#pragma unroll
        for (int nt = 0; nt < 4; ++nt) {
            int n = bn + wn + nt * 16 + cn;
            if (n < N) {
#pragma unroll
                for (int r = 0; r < 4; ++r) {
                    int m = bm + wm + mt * 16 + cm + r;
                    size_t idx = (size_t)m * N + n;
                    float v = acc[mt][nt][r];
                    if constexpr (ADD) v += ADDSRC[idx];
                    C[idx] = v;
                }
            }
        }
    }
}

// distinct names per call-site for rocprof visibility
__global__ __launch_bounds__(256) void gemm_in_kernel(
    const unsigned short* __restrict__ A, const unsigned short* __restrict__ B,
    float* __restrict__ C, int N, int K)
{ gemm_bf_body<0>(A, B, nullptr, C, N, K); }

__global__ __launch_bounds__(256) void gemm_out_kernel(
    const unsigned short* __restrict__ A, const unsigned short* __restrict__ B,
    const float* __restrict__ ADDSRC, float* __restrict__ C, int N, int K)
{ gemm_bf_body<1>(A, B, ADDSRC, C, N, K); }

__global__ __launch_bounds__(256) void gemm_xproj_kernel(
    const unsigned short* __restrict__ A, const unsigned short* __restrict__ B,
    float* __restrict__ C, int N, int K)
{ gemm_bf_body<0>(A, B, nullptr, C, N, K); }

__global__ __launch_bounds__(256) void gemm_logits_kernel(
    const unsigned short* __restrict__ A, const unsigned short* __restrict__ B,
    float* __restrict__ C, int N, int K)
{ gemm_bf_body<0>(A, B, nullptr, C, N, K); }

// ---------------------------------------------------------------------------
// fallback fp32 GEMM (R0 code, known-pass) for small-ws safety
// ---------------------------------------------------------------------------
template <int ADD>
__global__ __launch_bounds__(256) void gemm_fb_kernel(
    const float* __restrict__ A, const float* __restrict__ B,
    const float* __restrict__ ADDSRC, float* __restrict__ C,
    int N, int K)
{
    __shared__ unsigned short sA[128 * 40];
    __shared__ unsigned short sB[128 * 40];
    const int tid  = threadIdx.x;
    const int lane = tid & 63;
    const int wave = tid >> 6;
    const int wm = (wave & 1) * 64;
    const int wn = (wave >> 1) * 64;
    const int bm = blockIdx.y * 128;
    const int bn = blockIdx.x * 128;
    const int srow = tid >> 1;
    const int scol = (tid & 1) * 16;
    const float* Ap = A + (size_t)(bm + srow) * K + scol;
    const int brow  = bn + srow;
    const bool bvalid = brow < N;
    const float* Bp = B + (size_t)(bvalid ? brow : 0) * K + scol;
    f32x4 acc[4][4];
#pragma unroll
    for (int i = 0; i < 4; ++i)
#pragma unroll
        for (int j = 0; j < 4; ++j) acc[i][j] = (f32x4){0.f, 0.f, 0.f, 0.f};
    unsigned short* sAp = &sA[srow * 40 + scol];
    unsigned short* sBp = &sB[srow * 40 + scol];
    const int fr = (lane & 15) * 40 + (lane >> 4) * 8;
    for (int k0 = 0; k0 < K; k0 += 32) {
        float4 a0 = *(const float4*)(Ap + k0);
        float4 a1 = *(const float4*)(Ap + k0 + 4);
        float4 a2 = *(const float4*)(Ap + k0 + 8);
        float4 a3 = *(const float4*)(Ap + k0 + 12);
        float4 b0, b1, b2, b3;
        if (bvalid) {
            b0 = *(const float4*)(Bp + k0);
            b1 = *(const float4*)(Bp + k0 + 4);
            b2 = *(const float4*)(Bp + k0 + 8);
            b3 = *(const float4*)(Bp + k0 + 12);
        } else {
            b0 = make_float4(0.f, 0.f, 0.f, 0.f);
            b1 = b0; b2 = b0; b3 = b0;
        }
        __syncthreads();
        us8 va0 = { f2bf(a0.x), f2bf(a0.y), f2bf(a0.z), f2bf(a0.w),
                    f2bf(a1.x), f2bf(a1.y), f2bf(a1.z), f2bf(a1.w) };
        us8 va1 = { f2bf(a2.x), f2bf(a2.y), f2bf(a2.z), f2bf(a2.w),
                    f2bf(a3.x), f2bf(a3.y), f2bf(a3.z), f2bf(a3.w) };
        us8 vb0 = { f2bf(b0.x), f2bf(b0.y), f2bf(b0.z), f2bf(b0.w),
                    f2bf(b1.x), f2bf(b1.y), f2bf(b1.z), f2bf(b1.w) };
        us8 vb1 = { f2bf(b2.x), f2bf(b2.y), f2bf(b2.z), f2bf(b2.w),
                    f2bf(b3.x), f2bf(b3.y), f2bf(b3.z), f2bf(b3.w) };
        *(us8*)(sAp)     = va0;
        *(us8*)(sAp + 8) = va1;
        *(us8*)(sBp)     = vb0;
        *(us8*)(sBp + 8) = vb1;
        __syncthreads();
        bf16x8 af[4], bfr[4];
#pragma unroll
        for (int t = 0; t < 4; ++t) {
            af[t]  = __builtin_bit_cast(bf16x8, *(const us8*)&sA[wm * 40 + t * 640 + fr]);
            bfr[t] = __builtin_bit_cast(bf16x8, *(const us8*)&sB[wn * 40 + t * 640 + fr]);
        }
#pragma unroll
        for (int mt = 0; mt < 4; ++mt)
#pragma unroll
            for (int nt = 0; nt < 4; ++nt)
                acc[mt][nt] = __builtin_amdgcn_mfma_f32_16x16x32_bf16(
                    af[mt], bfr[nt], acc[mt][nt], 0, 0, 0);
    }
    const int cn = lane & 15;
    const int cm = (lane >> 4) * 4;
#pragma unroll
    for (int mt = 0; mt < 4; ++mt) {
#pragma unroll
        for (int nt = 0; nt < 4; ++nt) {
            int n = bn + wn + nt * 16 + cn;
            if (n < N) {
#pragma unroll
                for (int r = 0; r < 4; ++r) {
                    int m = bm + wm + mt * 16 + cm + r;
                    size_t idx = (size_t)m * N + n;
                    float v = acc[mt][nt][r];
                    if constexpr (ADD) v += ADDSRC[idx];
                    C[idx] = v;
                }
            }
        }
    }
}

// ---------------------------------------------------------------------------
__global__ __launch_bounds__(256) void embed_kernel(
    const int* __restrict__ ids, const float* __restrict__ emb, float* __restrict__ h)
{
    int l = blockIdx.x;
    int id = ids[l];
    const float* src = emb + (size_t)id * DMODEL;
    for (int d = threadIdx.x; d < DMODEL; d += 256) h[(size_t)l * DMODEL + d] = src[d];
}

template <typename OT>
__global__ __launch_bounds__(256) void rmsnorm_kernel(
    const float* __restrict__ x, const float* __restrict__ w,
    OT* __restrict__ out, int D)
{
    int l = blockIdx.x;
    const float* xr = x + (size_t)l * D;
    float ss = 0.f;
    for (int d = threadIdx.x; d < D; d += 256) { float v = xr[d]; ss += v * v; }
#pragma unroll
    for (int off = 32; off > 0; off >>= 1) ss += __shfl_down(ss, off, 64);
    __shared__ float red[4];
    __shared__ float invs;
    if ((threadIdx.x & 63) == 0) red[threadIdx.x >> 6] = ss;
    __syncthreads();
    if (threadIdx.x == 0)
        invs = rsqrtf((red[0] + red[1] + red[2] + red[3]) / (float)D + 1e-5f);
    __syncthreads();
    float inv = invs;
    for (int d = threadIdx.x; d < D; d += 256) {
        float v = xr[d] * inv * w[d];
        if constexpr (sizeof(OT) == 2) out[(size_t)l * D + d] = f2bf(v);
        else                           out[(size_t)l * D + d] = v;
    }
}

// conv+silu; emits fp32 xc (scan) and bf16 xcB (xproj GEMM A-operand)
__global__ __launch_bounds__(256) void conv_silu_kernel(
    const float* __restrict__ xz, const float* __restrict__ cw,
    const float* __restrict__ cb, float* __restrict__ xc,
    unsigned short* __restrict__ xcB)
{
    int l = blockIdx.x / 6;
    int d = (blockIdx.x % 6) * 256 + threadIdx.x;
    float w0 = cw[d * 4], w1 = cw[d * 4 + 1], w2 = cw[d * 4 + 2], w3 = cw[d * 4 + 3];
    float acc = cb[d];
    if (l >= 3) acc += xz[(size_t)(l - 3) * 3072 + d] * w0;
    if (l >= 2) acc += xz[(size_t)(l - 2) * 3072 + d] * w1;
    if (l >= 1) acc += xz[(size_t)(l - 1) * 3072 + d] * w2;
    acc += xz[(size_t)l * 3072 + d] * w3;
    float sig = 1.f / (1.f + __expf(-acc));
    float v = acc * sig;
    size_t idx = (size_t)l * DINNER + d;
    xc[idx]  = v;
    xcB[idx] = f2bf(v);
}

// fallback-only fp32 xproj (latency-bound; main path uses gemm_xproj_kernel)
__global__ __launch_bounds__(256) void xproj_kernel(
    const float* __restrict__ xc, const float* __restrict__ xw, float* __restrict__ dbl)
{
    int l = blockIdx.x;
    __shared__ float sx[DINNER];
    for (int d = threadIdx.x; d < DINNER; d += 256) sx[d] = xc[(size_t)l * DINNER + d];
    __syncthreads();
    int wave = threadIdx.x >> 6, lane = threadIdx.x & 63;
    for (int e = wave * 20; e < wave * 20 + 20; ++e) {
        const float* wr = xw + (size_t)e * DINNER;
        float s = 0.f;
        for (int d = lane; d < DINNER; d += 64) s += sx[d] * wr[d];
#pragma unroll
        for (int off = 32; off > 0; off >>= 1) s += __shfl_down(s, off, 64);
        if (lane == 0) dbl[l * 80 + e] = s;
    }
}

__global__ __launch_bounds__(256) void dtproj_kernel(
    const float* __restrict__ dbl, const float* __restrict__ dtw,
    const float* __restrict__ dtb, float* __restrict__ dt)
{
    int l = blockIdx.x / 6;
    int e = (blockIdx.x % 6) * 256 + threadIdx.x;
    __shared__ float sd[48];
    if (threadIdx.x < 48) sd[threadIdx.x] = dbl[l * 80 + threadIdx.x];
    __syncthreads();
    float a = dtb[e];
    const float4* wr = (const float4*)(dtw + (size_t)e * 48);
#pragma unroll
    for (int q = 0; q < 12; ++q) {
        float4 w4 = wr[q];
        a += sd[q * 4] * w4.x + sd[q * 4 + 1] * w4.y + sd[q * 4 + 2] * w4.z + sd[q * 4 + 3] * w4.w;
    }
    dt[(size_t)l * DINNER + e] = (a > 20.f) ? a : log1pf(__expf(a));
}

template <typename OT>
__global__ __launch_bounds__(64) void scan_kernel(
    const float* __restrict__ dt, const float* __restrict__ dbl,
    const float* __restrict__ xc, const float* __restrict__ xz,
    const float* __restrict__ alog, const float* __restrict__ dpar,
    OT* __restrict__ yf)
{
    int d0 = blockIdx.x * 4;
    int lane = threadIdx.x;
    int n = lane & 15;
    int dloc = lane >> 4;
    int d = d0 + dloc;
    float A = -__expf(alog[d * 16 + n]);
    float Dq[4];
#pragma unroll
    for (int q = 0; q < 4; ++q) Dq[q] = dpar[d0 + q];

    __shared__ float sdt[64][4];
    __shared__ float sxc[64][4];
    __shared__ float sz[64][4];
    __shared__ float sB[64][16];
    __shared__ float sC[64][16];
    __shared__ float pp[4][64][17];

    float s = 0.f;
    for (int c0 = 0; c0 < SEQL; c0 += 64) {
        int l = c0 + lane;
        *(float4*)&sdt[lane][0] = *(const float4*)&dt[(size_t)l * DINNER + d0];
        *(float4*)&sxc[lane][0] = *(const float4*)&xc[(size_t)l * DINNER + d0];
        *(float4*)&sz[lane][0]  = *(const float4*)&xz[(size_t)l * 3072 + DINNER + d0];
#pragma unroll
        for (int q = 0; q < 4; ++q) {
            *(float4*)&sB[lane][q * 4] = *(const float4*)&dbl[l * 80 + 48 + q * 4];
            *(float4*)&sC[lane][q * 4] = *(const float4*)&dbl[l * 80 + 64 + q * 4];
        }
        __syncthreads();
#pragma unroll 4
        for (int j = 0; j < 64; ++j) {
            float dtv = sdt[j][dloc];
            float xv  = sxc[j][dloc];
            float a = __expf(dtv * A);
            s = fmaf(a, s, dtv * sB[j][n] * xv);
            pp[dloc][j][n] = s * sC[j][n];
        }
        __syncthreads();
#pragma unroll
        for (int q = 0; q < 4; ++q) {
            float accv = 0.f;
#pragma unroll
            for (int nn = 0; nn < 16; ++nn) accv += pp[q][lane][nn];
            float xv = sxc[lane][q];
            float zv = sz[lane][q];
            float sig = 1.f / (1.f + __expf(-zv));
            float v = (accv + xv * Dq[q]) * (zv * sig);
            if constexpr (sizeof(OT) == 2) yf[(size_t)(c0 + lane) * DINNER + d0 + q] = f2bf(v);
            else                           yf[(size_t)(c0 + lane) * DINNER + d0 + q] = v;
        }
        __syncthreads();
    }
}

// ---------------------------------------------------------------------------
extern "C" void kernel_launch(void* const* d_in, const int* in_sizes, int n_in,
                              void* d_out, int out_size, void* d_ws, size_t ws_size,
                              hipStream_t stream)
{
    const int*   ids  = (const int*)d_in[0];
    const float* emb  = (const float*)d_in[1];
    const float* inw  = (const float*)d_in[2];
    const float* cw   = (const float*)d_in[3];
    const float* cb   = (const float*)d_in[4];
    const float* xw   = (const float*)d_in[5];
    const float* dtw  = (const float*)d_in[6];
    const float* dtb  = (const float*)d_in[7];
    const float* alog = (const float*)d_in[8];
    const float* dpar = (const float*)d_in[9];
    const float* ow   = (const float*)d_in[10];
    const float* nw   = (const float*)d_in[11];
    const float* nfw  = (const float*)d_in[12];
    float* out = (float*)d_out;

    const size_t MAIN_WS = 138936320ull;

    if (ws_size >= MAIN_WS) {
        char* p = (char*)d_ws;
        float* h    = (float*)p;                 p += (size_t)SEQL * DMODEL * 4;
        float* xz   = (float*)p;                 p += (size_t)SEQL * 3072 * 4;
        float* xc   = (float*)p;                 p += (size_t)SEQL * DINNER * 4;
        float* dbl  = (float*)p;                 p += (size_t)SEQL * 80 * 4;
        float* dt   = (float*)p;                 p += (size_t)SEQL * DINNER * 4;
        unsigned short* xnB  = (unsigned short*)p; p += (size_t)SEQL * DMODEL * 2;
        unsigned short* yfB  = (unsigned short*)p; p += (size_t)SEQL * DINNER * 2;
        unsigned short* embB = (unsigned short*)p; p += (size_t)VOCABPAD * DMODEL * 2;
        unsigned short* inwB = (unsigned short*)p; p += (size_t)N_LAYER * 3072 * DMODEL * 2;
        unsigned short* owB  = (unsigned short*)p; p += (size_t)N_LAYER * DMODEL * DINNER * 2;

        // scratch in the (huge, write-only-at-end) logits output buffer:
        // xwB: 4*128*1536 bf16 (1.5 MB), xcB: 1024*1536 bf16 (3 MB); both
        // fully consumed before gemm_logits writes out. No MAIN_WS growth.
        unsigned short* xwB = (unsigned short*)out;
        unsigned short* xcB = xwB + (size_t)N_LAYER * 128 * DINNER;

        int n8;
        n8 = VOCABSZ * DMODEL / 8;
        cvt_bf16_kernel<<<(n8 + 255) / 256, 256, 0, stream>>>(emb, embB, n8);
        n8 = N_LAYER * 3072 * DMODEL / 8;
        cvt_bf16_kernel<<<(n8 + 255) / 256, 256, 0, stream>>>(inw, inwB, n8);
        n8 = N_LAYER * DMODEL * DINNER / 8;
        cvt_bf16_kernel<<<(n8 + 255) / 256, 256, 0, stream>>>(ow, owB, n8);
        cvt_xw_kernel<<<(N_LAYER * 128 * 192 + 255) / 256, 256, 0, stream>>>(xw, xwB);

        embed_kernel<<<SEQL, 256, 0, stream>>>(ids, emb, h);

        for (int i = 0; i < N_LAYER; ++i) {
            rmsnorm_kernel<unsigned short><<<SEQL, 256, 0, stream>>>(
                h, nw + (size_t)i * DMODEL, xnB, DMODEL);
            gemm_in_kernel<<<8 * (3072 / 128), 256, 0, stream>>>(
                xnB, inwB + (size_t)i * 3072 * DMODEL, xz, 3072, DMODEL);
            conv_silu_kernel<<<SEQL * 6, 256, 0, stream>>>(
                xz, cw + (size_t)i * DINNER * 4, cb + (size_t)i * DINNER, xc, xcB);
            gemm_xproj_kernel<<<8, 256, 0, stream>>>(
                xcB, xwB + (size_t)i * 128 * DINNER, dbl, 80, DINNER);
            dtproj_kernel<<<SEQL * 6, 256, 0, stream>>>(
                dbl, dtw + (size_t)i * DINNER * DTRANK, dtb + (size_t)i * DINNER, dt);
            scan_kernel<unsigned short><<<DINNER / 4, 64, 0, stream>>>(
                dt, dbl, xc, xz, alog + (size_t)i * DINNER * DSTATE,
                dpar + (size_t)i * DINNER, yfB);
            gemm_out_kernel<<<8 * (DMODEL / 128), 256, 0, stream>>>(
                yfB, owB + (size_t)i * DMODEL * DINNER, h, h, DMODEL, DINNER);
        }

        rmsnorm_kernel<unsigned short><<<SEQL, 256, 0, stream>>>(h, nfw, xnB, DMODEL);
        gemm_logits_kernel<<<8 * ((VOCABSZ + 127) / 128), 256, 0, stream>>>(
            xnB, embB, out, VOCABSZ, DMODEL);
    } else {
        // fallback: R0 fp32 path (ws >= 38 MB verified)
        float* h   = (float*)d_ws;
        float* xn  = h  + (size_t)SEQL * DMODEL;
        float* xz  = xn + (size_t)SEQL * DMODEL;
        float* xc  = xz + (size_t)SEQL * 3072;
        float* dbl = xc + (size_t)SEQL * DINNER;
        float* dt  = dbl + (size_t)SEQL * 80;
        float* yf  = dt + (size_t)SEQL * DINNER;
        unsigned short* xcB = (unsigned short*)out;   // scratch, overwritten at end

        embed_kernel<<<SEQL, 256, 0, stream>>>(ids, emb, h);
        for (int i = 0; i < N_LAYER; ++i) {
            rmsnorm_kernel<float><<<SEQL, 256, 0, stream>>>(h, nw + (size_t)i * DMODEL, xn, DMODEL);
            gemm_fb_kernel<0><<<dim3(3072 / 128, SEQL / 128), 256, 0, stream>>>(
                xn, inw + (size_t)i * 3072 * DMODEL, nullptr, xz, 3072, DMODEL);
            conv_silu_kernel<<<SEQL * 6, 256, 0, stream>>>(
                xz, cw + (size_t)i * DINNER * 4, cb + (size_t)i * DINNER, xc, xcB);
            xproj_kernel<<<SEQL, 256, 0, stream>>>(xc, xw + (size_t)i * 80 * DINNER, dbl);
            dtproj_kernel<<<SEQL * 6, 256, 0, stream>>>(
                dbl, dtw + (size_t)i * DINNER * DTRANK, dtb + (size_t)i * DINNER, dt);
            scan_kernel<float><<<DINNER / 4, 64, 0, stream>>>(
                dt, dbl, xc, xz, alog + (size_t)i * DINNER * DSTATE, dpar + (size_t)i * DINNER, yf);
            gemm_fb_kernel<1><<<dim3(DMODEL / 128, SEQL / 128), 256, 0, stream>>>(
                yf, ow + (size_t)i * DMODEL * DINNER, h, h, DMODEL, DINNER);
        }
        rmsnorm_kernel<float><<<SEQL, 256, 0, stream>>>(h, nfw, xn, DMODEL);
        gemm_fb_kernel<0><<<dim3((VOCABSZ + 127) / 128, SEQL / 128), 256, 0, stream>>>(
            xn, emb, nullptr, out, VOCABSZ, DMODEL);
    }
}

// Round 5
// 1220.876 us; speedup vs baseline: 1.0577x; 1.0577x over previous
//
#include <hip/hip_runtime.h>
#include <cstdint>
#include <cstddef>

#define N_LAYER 4
#define VOCABSZ 50280
#define VOCABPAD 50304
#define DMODEL 768
#define DINNER 1536
#define DSTATE 16
#define DTRANK 48
#define SEQL 1024

typedef __bf16 bf16x8 __attribute__((ext_vector_type(8)));
typedef unsigned short us8 __attribute__((ext_vector_type(8)));
typedef float f32x4 __attribute__((ext_vector_type(4)));

__device__ __forceinline__ unsigned short f2bf(float f) {
    unsigned int u = __builtin_bit_cast(unsigned int, f);
    u = (u + 0x7FFFu + ((u >> 16) & 1u)) >> 16;   // round-to-nearest-even
    return (unsigned short)u;
}

__device__ __forceinline__ void glds16(const unsigned short* g, unsigned short* l) {
    __builtin_amdgcn_global_load_lds(
        (const __attribute__((address_space(1))) void*)g,
        (__attribute__((address_space(3))) void*)l, 16, 0, 0);
}

// ---------------------------------------------------------------------------
// fp32 -> bf16 bulk convert (8 elems/thread)
// ---------------------------------------------------------------------------
__global__ __launch_bounds__(256) void cvt_bf16_kernel(
    const float* __restrict__ src, unsigned short* __restrict__ dst, int n8)
{
    int i = blockIdx.x * 256 + threadIdx.x;
    if (i >= n8) return;
    const float4* s = (const float4*)src + (size_t)i * 2;
    float4 a = s[0], b = s[1];
    us8 o = { f2bf(a.x), f2bf(a.y), f2bf(a.z), f2bf(a.w),
              f2bf(b.x), f2bf(b.y), f2bf(b.z), f2bf(b.w) };
    *(us8*)(dst + (size_t)i * 8) = o;
}

// ---------------------------------------------------------------------------
// x_proj_w (N_LAYER,80,1536) fp32 -> bf16, padded to 128 rows/layer (rows>=80
// zeroed so the 128-row GEMM staging reads defined data). 8 cols/thread.
// ---------------------------------------------------------------------------
__global__ __launch_bounds__(256) void cvt_xw_kernel(
    const float* __restrict__ xw, unsigned short* __restrict__ xwB)
{
    int g = blockIdx.x * 256 + threadIdx.x;
    if (g >= N_LAYER * 128 * 192) return;
    int row = g / 192;              // padded row 0 .. 4*128-1
    int c8  = g % 192;
    int layer = row >> 7;
    int r = row & 127;
    us8 o;
    if (r < 80) {
        const float4* s = (const float4*)(xw + ((size_t)(layer * 80 + r) * DINNER) + c8 * 8);
        float4 a = s[0], b = s[1];
        o = (us8){ f2bf(a.x), f2bf(a.y), f2bf(a.z), f2bf(a.w),
                   f2bf(b.x), f2bf(b.y), f2bf(b.z), f2bf(b.w) };
    } else {
        o = (us8){0, 0, 0, 0, 0, 0, 0, 0};
    }
    *(us8*)(xwB + (size_t)row * DINNER + c8 * 8) = o;
}

// ---------------------------------------------------------------------------
// bf16 NT GEMM: C[m,n] = sum_k A[m,k]*B[n,k] (+ADDSRC)
// 128x128 tile, BK=32, 4 waves. R5 structure:
//  - T3 minimum 2-phase: double-buffered LDS (static names, unrolled x2);
//    next tile's global_load_lds issued BEFORE computing current tile; ONE
//    __syncthreads (vmcnt drain) per 32-K-step. Hides staging latency that
//    the R4 1-phase loop exposed every iteration.
//  - G4 bank-swizzle (both-sides, rule #21): glds dest stays linear, global
//    SOURCE chunk pre-swizzled by (row>>1)&3; ds_read XORs the same term.
//    Lanes 0-15 now hit 8 distinct bank-quads (2-way = free) instead of
//    4-8-way (9.66M conflict cycles measured in R4).
//  - XCD-bijective swizzle (R2-proven: FETCH 307->108 MB). grid%8==0 for all
//    users (192/48/8/3144); K%64==0 for all users (768/1536).
// ---------------------------------------------------------------------------
__device__ __forceinline__ void gemm_compute32(
    const unsigned short* sAbuf, const unsigned short* sBbuf,
    int wm, int wn, int frs, f32x4 (&acc)[4][4])
{
    bf16x8 af[4], bfr[4];
#pragma unroll
    for (int t = 0; t < 4; ++t) {
        af[t]  = __builtin_bit_cast(bf16x8, *(const us8*)&sAbuf[(wm + t * 16) * 32 + frs]);
        bfr[t] = __builtin_bit_cast(bf16x8, *(const us8*)&sBbuf[(wn + t * 16) * 32 + frs]);
    }
#pragma unroll
    for (int mt = 0; mt < 4; ++mt)
#pragma unroll
        for (int nt = 0; nt < 4; ++nt)
            acc[mt][nt] = __builtin_amdgcn_mfma_f32_16x16x32_bf16(
                af[mt], bfr[nt], acc[mt][nt], 0, 0, 0);
}

template <int ADD>
__device__ __forceinline__ void gemm_bf_body(
    const unsigned short* __restrict__ A, const unsigned short* __restrict__ B,
    const float* __restrict__ ADDSRC, float* __restrict__ C, int N, int K)
{
    __shared__ unsigned short sA0[128 * 32];
    __shared__ unsigned short sA1[128 * 32];
    __shared__ unsigned short sB0[128 * 32];
    __shared__ unsigned short sB1[128 * 32];

    const int tid  = threadIdx.x;
    const int lane = tid & 63;
    const int wave = tid >> 6;
    const int wm = (wave & 1) * 64;
    const int wn = (wave >> 1) * 64;
    const int bid = blockIdx.x;
    const int cpx = (int)gridDim.x >> 3;
    const int swz = (bid & 7) * cpx + (bid >> 3);
    const int bm = (swz & 7) << 7;
    const int bn = (swz >> 3) << 7;

    // staging: thread t -> LDS row t>>2 (and 64+(t>>2)), chunk t&3 (16B).
    // bank-swizzle: source chunk = (t&3) ^ ((row>>1)&3); (t>>3) == row>>1.
    const int scol = ((tid & 3) ^ ((tid >> 3) & 3)) * 8;
    const unsigned short* Ag0 = A + (size_t)(bm + (tid >> 2)) * K + scol;
    const unsigned short* Ag1 = Ag0 + (size_t)64 * K;
    const unsigned short* Bg0 = B + (size_t)(bn + (tid >> 2)) * K + scol;
    const unsigned short* Bg1 = Bg0 + (size_t)64 * K;
    unsigned short* lA0a = sA0 + tid * 8;  unsigned short* lA0b = lA0a + 2048;
    unsigned short* lA1a = sA1 + tid * 8;  unsigned short* lA1b = lA1a + 2048;
    unsigned short* lB0a = sB0 + tid * 8;  unsigned short* lB0b = lB0a + 2048;
    unsigned short* lB1a = sB1 + tid * 8;  unsigned short* lB1b = lB1a + 2048;

    f32x4 acc[4][4];
#pragma unroll
    for (int i = 0; i < 4; ++i)
#pragma unroll
        for (int j = 0; j < 4; ++j) acc[i][j] = (f32x4){0.f, 0.f, 0.f, 0.f};

    // read offset: row (lane&15), chunk (lane>>4) ^ ((row>>1)&3)
    const int frs = (lane & 15) * 32 + (((lane >> 4) ^ ((lane >> 1) & 3))) * 8;

    // prologue: stage k=0 into buf0
    glds16(Ag0, lA0a); glds16(Ag1, lA0b);
    glds16(Bg0, lB0a); glds16(Bg1, lB0b);
    Ag0 += 32; Ag1 += 32; Bg0 += 32; Bg1 += 32;
    __syncthreads();                           // buf0 ready

    for (int k0 = 0; k0 < K; k0 += 64) {
        // stage k0+32 into buf1 (always valid: k0+32 <= K-32), then compute buf0
        glds16(Ag0, lA1a); glds16(Ag1, lA1b);
        glds16(Bg0, lB1a); glds16(Bg1, lB1b);
        Ag0 += 32; Ag1 += 32; Bg0 += 32; Bg1 += 32;
        gemm_compute32(sA0, sB0, wm, wn, frs, acc);
        __syncthreads();                       // buf1 ready; buf0 reads done

        if (k0 + 64 < K) {                     // uniform branch
            glds16(Ag0, lA0a); glds16(Ag1, lA0b);
            glds16(Bg0, lB0a); glds16(Bg1, lB0b);
            Ag0 += 32; Ag1 += 32; Bg0 += 32; Bg1 += 32;
        }
        gemm_compute32(sA1, sB1, wm, wn, frs, acc);
        __syncthreads();                       // buf0 ready; buf1 reads done
    }

    const int cn = lane & 15;
    const int cm = (lane >> 4) * 4;
#pragma unroll
    for (int mt = 0; mt < 4; ++mt) {
#pragma unroll
        for (int nt = 0; nt < 4; ++nt) {
            int n = bn + wn + nt * 16 + cn;
            if (n < N) {
#pragma unroll
                for (int r = 0; r < 4; ++r) {
                    int m = bm + wm + mt * 16 + cm + r;
                    size_t idx = (size_t)m * N + n;
                    float v = acc[mt][nt][r];
                    if constexpr (ADD) v += ADDSRC[idx];
                    C[idx] = v;
                }
            }
        }
    }
}

// distinct names per call-site for rocprof visibility
__global__ __launch_bounds__(256) void gemm_in_kernel(
    const unsigned short* __restrict__ A, const unsigned short* __restrict__ B,
    float* __restrict__ C, int N, int K)
{ gemm_bf_body<0>(A, B, nullptr, C, N, K); }

__global__ __launch_bounds__(256) void gemm_out_kernel(
    const unsigned short* __restrict__ A, const unsigned short* __restrict__ B,
    const float* __restrict__ ADDSRC, float* __restrict__ C, int N, int K)
{ gemm_bf_body<1>(A, B, ADDSRC, C, N, K); }

__global__ __launch_bounds__(256) void gemm_xproj_kernel(
    const unsigned short* __restrict__ A, const unsigned short* __restrict__ B,
    float* __restrict__ C, int N, int K)
{ gemm_bf_body<0>(A, B, nullptr, C, N, K); }

__global__ __launch_bounds__(256) void gemm_logits_kernel(
    const unsigned short* __restrict__ A, const unsigned short* __restrict__ B,
    float* __restrict__ C, int N, int K)
{ gemm_bf_body<0>(A, B, nullptr, C, N, K); }

// ---------------------------------------------------------------------------
// fallback fp32 GEMM (R0 code, known-pass) for small-ws safety
// ---------------------------------------------------------------------------
template <int ADD>
__global__ __launch_bounds__(256) void gemm_fb_kernel(
    const float* __restrict__ A, const float* __restrict__ B,
    const float* __restrict__ ADDSRC, float* __restrict__ C,
    int N, int K)
{
    __shared__ unsigned short sA[128 * 40];
    __shared__ unsigned short sB[128 * 40];
    const int tid  = threadIdx.x;
    const int lane = tid & 63;
    const int wave = tid >> 6;
    const int wm = (wave & 1) * 64;
    const int wn = (wave >> 1) * 64;
    const int bm = blockIdx.y * 128;
    const int bn = blockIdx.x * 128;
    const int srow = tid >> 1;
    const int scol = (tid & 1) * 16;
    const float* Ap = A + (size_t)(bm + srow) * K + scol;
    const int brow  = bn + srow;
    const bool bvalid = brow < N;
    const float* Bp = B + (size_t)(bvalid ? brow : 0) * K + scol;
    f32x4 acc[4][4];
#pragma unroll
    for (int i = 0; i < 4; ++i)
#pragma unroll
        for (int j = 0; j < 4; ++j) acc[i][j] = (f32x4){0.f, 0.f, 0.f, 0.f};
    unsigned short* sAp = &sA[srow * 40 + scol];
    unsigned short* sBp = &sB[srow * 40 + scol];
    const int fr = (lane & 15) * 40 + (lane >> 4) * 8;
    for (int k0 = 0; k0 < K; k0 += 32) {
        float4 a0 = *(const float4*)(Ap + k0);
        float4 a1 = *(const float4*)(Ap + k0 + 4);
        float4 a2 = *(const float4*)(Ap + k0 + 8);
        float4 a3 = *(const float4*)(Ap + k0 + 12);
        float4 b0, b1, b2, b3;
        if (bvalid) {
            b0 = *(const float4*)(Bp + k0);
            b1 = *(const float4*)(Bp + k0 + 4);
            b2 = *(const float4*)(Bp + k0 + 8);
            b3 = *(const float4*)(Bp + k0 + 12);
        } else {
            b0 = make_float4(0.f, 0.f, 0.f, 0.f);
            b1 = b0; b2 = b0; b3 = b0;
        }
        __syncthreads();
        us8 va0 = { f2bf(a0.x), f2bf(a0.y), f2bf(a0.z), f2bf(a0.w),
                    f2bf(a1.x), f2bf(a1.y), f2bf(a1.z), f2bf(a1.w) };
        us8 va1 = { f2bf(a2.x), f2bf(a2.y), f2bf(a2.z), f2bf(a2.w),
                    f2bf(a3.x), f2bf(a3.y), f2bf(a3.z), f2bf(a3.w) };
        us8 vb0 = { f2bf(b0.x), f2bf(b0.y), f2bf(b0.z), f2bf(b0.w),
                    f2bf(b1.x), f2bf(b1.y), f2bf(b1.z), f2bf(b1.w) };
        us8 vb1 = { f2bf(b2.x), f2bf(b2.y), f2bf(b2.z), f2bf(b2.w),
                    f2bf(b3.x), f2bf(b3.y), f2bf(b3.z), f2bf(b3.w) };
        *(us8*)(sAp)     = va0;
        *(us8*)(sAp + 8) = va1;
        *(us8*)(sBp)     = vb0;
        *(us8*)(sBp + 8) = vb1;
        __syncthreads();
        bf16x8 af[4], bfr[4];
#pragma unroll
        for (int t = 0; t < 4; ++t) {
            af[t]  = __builtin_bit_cast(bf16x8, *(const us8*)&sA[wm * 40 + t * 640 + fr]);
            bfr[t] = __builtin_bit_cast(bf16x8, *(const us8*)&sB[wn * 40 + t * 640 + fr]);
        }
#pragma unroll
        for (int mt = 0; mt < 4; ++mt)
#pragma unroll
            for (int nt = 0; nt < 4; ++nt)
                acc[mt][nt] = __builtin_amdgcn_mfma_f32_16x16x32_bf16(
                    af[mt], bfr[nt], acc[mt][nt], 0, 0, 0);
    }
    const int cn = lane & 15;
    const int cm = (lane >> 4) * 4;
#pragma unroll
    for (int mt = 0; mt < 4; ++mt) {
#pragma unroll
        for (int nt = 0; nt < 4; ++nt) {
            int n = bn + wn + nt * 16 + cn;
            if (n < N) {
#pragma unroll
                for (int r = 0; r < 4; ++r) {
                    int m = bm + wm + mt * 16 + cm + r;
                    size_t idx = (size_t)m * N + n;
                    float v = acc[mt][nt][r];
                    if constexpr (ADD) v += ADDSRC[idx];
                    C[idx] = v;
                }
            }
        }
    }
}

// ---------------------------------------------------------------------------
__global__ __launch_bounds__(256) void embed_kernel(
    const int* __restrict__ ids, const float* __restrict__ emb, float* __restrict__ h)
{
    int l = blockIdx.x;
    int id = ids[l];
    const float* src = emb + (size_t)id * DMODEL;
    for (int d = threadIdx.x; d < DMODEL; d += 256) h[(size_t)l * DMODEL + d] = src[d];
}

template <typename OT>
__global__ __launch_bounds__(256) void rmsnorm_kernel(
    const float* __restrict__ x, const float* __restrict__ w,
    OT* __restrict__ out, int D)
{
    int l = blockIdx.x;
    const float* xr = x + (size_t)l * D;
    float ss = 0.f;
    for (int d = threadIdx.x; d < D; d += 256) { float v = xr[d]; ss += v * v; }
#pragma unroll
    for (int off = 32; off > 0; off >>= 1) ss += __shfl_down(ss, off, 64);
    __shared__ float red[4];
    __shared__ float invs;
    if ((threadIdx.x & 63) == 0) red[threadIdx.x >> 6] = ss;
    __syncthreads();
    if (threadIdx.x == 0)
        invs = rsqrtf((red[0] + red[1] + red[2] + red[3]) / (float)D + 1e-5f);
    __syncthreads();
    float inv = invs;
    for (int d = threadIdx.x; d < D; d += 256) {
        float v = xr[d] * inv * w[d];
        if constexpr (sizeof(OT) == 2) out[(size_t)l * D + d] = f2bf(v);
        else                           out[(size_t)l * D + d] = v;
    }
}

// conv+silu; emits fp32 xc (scan) and bf16 xcB (xproj GEMM A-operand)
__global__ __launch_bounds__(256) void conv_silu_kernel(
    const float* __restrict__ xz, const float* __restrict__ cw,
    const float* __restrict__ cb, float* __restrict__ xc,
    unsigned short* __restrict__ xcB)
{
    int l = blockIdx.x / 6;
    int d = (blockIdx.x % 6) * 256 + threadIdx.x;
    float w0 = cw[d * 4], w1 = cw[d * 4 + 1], w2 = cw[d * 4 + 2], w3 = cw[d * 4 + 3];
    float acc = cb[d];
    if (l >= 3) acc += xz[(size_t)(l - 3) * 3072 + d] * w0;
    if (l >= 2) acc += xz[(size_t)(l - 2) * 3072 + d] * w1;
    if (l >= 1) acc += xz[(size_t)(l - 1) * 3072 + d] * w2;
    acc += xz[(size_t)l * 3072 + d] * w3;
    float sig = 1.f / (1.f + __expf(-acc));
    float v = acc * sig;
    size_t idx = (size_t)l * DINNER + d;
    xc[idx]  = v;
    xcB[idx] = f2bf(v);
}

// fallback-only fp32 xproj (latency-bound; main path uses gemm_xproj_kernel)
__global__ __launch_bounds__(256) void xproj_kernel(
    const float* __restrict__ xc, const float* __restrict__ xw, float* __restrict__ dbl)
{
    int l = blockIdx.x;
    __shared__ float sx[DINNER];
    for (int d = threadIdx.x; d < DINNER; d += 256) sx[d] = xc[(size_t)l * DINNER + d];
    __syncthreads();
    int wave = threadIdx.x >> 6, lane = threadIdx.x & 63;
    for (int e = wave * 20; e < wave * 20 + 20; ++e) {
        const float* wr = xw + (size_t)e * DINNER;
        float s = 0.f;
        for (int d = lane; d < DINNER; d += 64) s += sx[d] * wr[d];
#pragma unroll
        for (int off = 32; off > 0; off >>= 1) s += __shfl_down(s, off, 64);
        if (lane == 0) dbl[l * 80 + e] = s;
    }
}

__global__ __launch_bounds__(256) void dtproj_kernel(
    const float* __restrict__ dbl, const float* __restrict__ dtw,
    const float* __restrict__ dtb, float* __restrict__ dt)
{
    int l = blockIdx.x / 6;
    int e = (blockIdx.x % 6) * 256 + threadIdx.x;
    __shared__ float sd[48];
    if (threadIdx.x < 48) sd[threadIdx.x] = dbl[l * 80 + threadIdx.x];
    __syncthreads();
    float a = dtb[e];
    const float4* wr = (const float4*)(dtw + (size_t)e * 48);
#pragma unroll
    for (int q = 0; q < 12; ++q) {
        float4 w4 = wr[q];
        a += sd[q * 4] * w4.x + sd[q * 4 + 1] * w4.y + sd[q * 4 + 2] * w4.z + sd[q * 4 + 3] * w4.w;
    }
    dt[(size_t)l * DINNER + e] = (a > 20.f) ? a : log1pf(__expf(a));
}

template <typename OT>
__global__ __launch_bounds__(64) void scan_kernel(
    const float* __restrict__ dt, const float* __restrict__ dbl,
    const float* __restrict__ xc, const float* __restrict__ xz,
    const float* __restrict__ alog, const float* __restrict__ dpar,
    OT* __restrict__ yf)
{
    int d0 = blockIdx.x * 4;
    int lane = threadIdx.x;
    int n = lane & 15;
    int dloc = lane >> 4;
    int d = d0 + dloc;
    float A = -__expf(alog[d * 16 + n]);
    float Dq[4];
#pragma unroll
    for (int q = 0; q < 4; ++q) Dq[q] = dpar[d0 + q];

    __shared__ float sdt[64][4];
    __shared__ float sxc[64][4];
    __shared__ float sz[64][4];
    __shared__ float sB[64][16];
    __shared__ float sC[64][16];
    __shared__ float pp[4][64][17];

    float s = 0.f;
    for (int c0 = 0; c0 < SEQL; c0 += 64) {
        int l = c0 + lane;
        *(float4*)&sdt[lane][0] = *(const float4*)&dt[(size_t)l * DINNER + d0];
        *(float4*)&sxc[lane][0] = *(const float4*)&xc[(size_t)l * DINNER + d0];
        *(float4*)&sz[lane][0]  = *(const float4*)&xz[(size_t)l * 3072 + DINNER + d0];
#pragma unroll
        for (int q = 0; q < 4; ++q) {
            *(float4*)&sB[lane][q * 4] = *(const float4*)&dbl[l * 80 + 48 + q * 4];
            *(float4*)&sC[lane][q * 4] = *(const float4*)&dbl[l * 80 + 64 + q * 4];
        }
        __syncthreads();
#pragma unroll 4
        for (int j = 0; j < 64; ++j) {
            float dtv = sdt[j][dloc];
            float xv  = sxc[j][dloc];
            float a = __expf(dtv * A);
            s = fmaf(a, s, dtv * sB[j][n] * xv);
            pp[dloc][j][n] = s * sC[j][n];
        }
        __syncthreads();
#pragma unroll
        for (int q = 0; q < 4; ++q) {
            float accv = 0.f;
#pragma unroll
            for (int nn = 0; nn < 16; ++nn) accv += pp[q][lane][nn];
            float xv = sxc[lane][q];
            float zv = sz[lane][q];
            float sig = 1.f / (1.f + __expf(-zv));
            float v = (accv + xv * Dq[q]) * (zv * sig);
            if constexpr (sizeof(OT) == 2) yf[(size_t)(c0 + lane) * DINNER + d0 + q] = f2bf(v);
            else                           yf[(size_t)(c0 + lane) * DINNER + d0 + q] = v;
        }
        __syncthreads();
    }
}

// ---------------------------------------------------------------------------
extern "C" void kernel_launch(void* const* d_in, const int* in_sizes, int n_in,
                              void* d_out, int out_size, void* d_ws, size_t ws_size,
                              hipStream_t stream)
{
    const int*   ids  = (const int*)d_in[0];
    const float* emb  = (const float*)d_in[1];
    const float* inw  = (const float*)d_in[2];
    const float* cw   = (const float*)d_in[3];
    const float* cb   = (const float*)d_in[4];
    const float* xw   = (const float*)d_in[5];
    const float* dtw  = (const float*)d_in[6];
    const float* dtb  = (const float*)d_in[7];
    const float* alog = (const float*)d_in[8];
    const float* dpar = (const float*)d_in[9];
    const float* ow   = (const float*)d_in[10];
    const float* nw   = (const float*)d_in[11];
    const float* nfw  = (const float*)d_in[12];
    float* out = (float*)d_out;

    const size_t MAIN_WS = 138936320ull;

    if (ws_size >= MAIN_WS) {
        char* p = (char*)d_ws;
        float* h    = (float*)p;                 p += (size_t)SEQL * DMODEL * 4;
        float* xz   = (float*)p;                 p += (size_t)SEQL * 3072 * 4;
        float* xc   = (float*)p;                 p += (size_t)SEQL * DINNER * 4;
        float* dbl  = (float*)p;                 p += (size_t)SEQL * 80 * 4;
        float* dt   = (float*)p;                 p += (size_t)SEQL * DINNER * 4;
        unsigned short* xnB  = (unsigned short*)p; p += (size_t)SEQL * DMODEL * 2;
        unsigned short* yfB  = (unsigned short*)p; p += (size_t)SEQL * DINNER * 2;
        unsigned short* embB = (unsigned short*)p; p += (size_t)VOCABPAD * DMODEL * 2;
        unsigned short* inwB = (unsigned short*)p; p += (size_t)N_LAYER * 3072 * DMODEL * 2;
        unsigned short* owB  = (unsigned short*)p; p += (size_t)N_LAYER * DMODEL * DINNER * 2;

        // scratch in the (huge, write-only-at-end) logits output buffer:
        // xwB: 4*128*1536 bf16 (1.5 MB), xcB: 1024*1536 bf16 (3 MB); both
        // fully consumed before gemm_logits writes out. No MAIN_WS growth.
        unsigned short* xwB = (unsigned short*)out;
        unsigned short* xcB = xwB + (size_t)N_LAYER * 128 * DINNER;

        int n8;
        n8 = VOCABSZ * DMODEL / 8;
        cvt_bf16_kernel<<<(n8 + 255) / 256, 256, 0, stream>>>(emb, embB, n8);
        n8 = N_LAYER * 3072 * DMODEL / 8;
        cvt_bf16_kernel<<<(n8 + 255) / 256, 256, 0, stream>>>(inw, inwB, n8);
        n8 = N_LAYER * DMODEL * DINNER / 8;
        cvt_bf16_kernel<<<(n8 + 255) / 256, 256, 0, stream>>>(ow, owB, n8);
        cvt_xw_kernel<<<(N_LAYER * 128 * 192 + 255) / 256, 256, 0, stream>>>(xw, xwB);

        embed_kernel<<<SEQL, 256, 0, stream>>>(ids, emb, h);

        for (int i = 0; i < N_LAYER; ++i) {
            rmsnorm_kernel<unsigned short><<<SEQL, 256, 0, stream>>>(
                h, nw + (size_t)i * DMODEL, xnB, DMODEL);
            gemm_in_kernel<<<8 * (3072 / 128), 256, 0, stream>>>(
                xnB, inwB + (size_t)i * 3072 * DMODEL, xz, 3072, DMODEL);
            conv_silu_kernel<<<SEQL * 6, 256, 0, stream>>>(
                xz, cw + (size_t)i * DINNER * 4, cb + (size_t)i * DINNER, xc, xcB);
            gemm_xproj_kernel<<<8, 256, 0, stream>>>(
                xcB, xwB + (size_t)i * 128 * DINNER, dbl, 80, DINNER);
            dtproj_kernel<<<SEQL * 6, 256, 0, stream>>>(
                dbl, dtw + (size_t)i * DINNER * DTRANK, dtb + (size_t)i * DINNER, dt);
            scan_kernel<unsigned short><<<DINNER / 4, 64, 0, stream>>>(
                dt, dbl, xc, xz, alog + (size_t)i * DINNER * DSTATE,
                dpar + (size_t)i * DINNER, yfB);
            gemm_out_kernel<<<8 * (DMODEL / 128), 256, 0, stream>>>(
                yfB, owB + (size_t)i * DMODEL * DINNER, h, h, DMODEL, DINNER);
        }

        rmsnorm_kernel<unsigned short><<<SEQL, 256, 0, stream>>>(h, nfw, xnB, DMODEL);
        gemm_logits_kernel<<<8 * ((VOCABSZ + 127) / 128), 256, 0, stream>>>(
            xnB, embB, out, VOCABSZ, DMODEL);
    } else {
        // fallback: R0 fp32 path (ws >= 38 MB verified)
        float* h   = (float*)d_ws;
        float* xn  = h  + (size_t)SEQL * DMODEL;
        float* xz  = xn + (size_t)SEQL * DMODEL;
        float* xc  = xz + (size_t)SEQL * 3072;
        float* dbl = xc + (size_t)SEQL * DINNER;
        float* dt  = dbl + (size_t)SEQL * 80;
        float* yf  = dt + (size_t)SEQL * DINNER;
        unsigned short* xcB = (unsigned short*)out;   // scratch, overwritten at end

        embed_kernel<<<SEQL, 256, 0, stream>>>(ids, emb, h);
        for (int i = 0; i < N_LAYER; ++i) {
            rmsnorm_kernel<float><<<SEQL, 256, 0, stream>>>(h, nw + (size_t)i * DMODEL, xn, DMODEL);
            gemm_fb_kernel<0><<<dim3(3072 / 128, SEQL / 128), 256, 0, stream>>>(
                xn, inw + (size_t)i * 3072 * DMODEL, nullptr, xz, 3072, DMODEL);
            conv_silu_kernel<<<SEQL * 6, 256, 0, stream>>>(
                xz, cw + (size_t)i * DINNER * 4, cb + (size_t)i * DINNER, xc, xcB);
            xproj_kernel<<<SEQL, 256, 0, stream>>>(xc, xw + (size_t)i * 80 * DINNER, dbl);
            dtproj_kernel<<<SEQL * 6, 256, 0, stream>>>(
                dbl, dtw + (size_t)i * DINNER * DTRANK, dtb + (size_t)i * DINNER, dt);
            scan_kernel<float><<<DINNER / 4, 64, 0, stream>>>(
                dt, dbl, xc, xz, alog + (size_t)i * DINNER * DSTATE, dpar + (size_t)i * DINNER, yf);
            gemm_fb_kernel<1><<<dim3(DMODEL / 128, SEQL / 128), 256, 0, stream>>>(
                yf, ow + (size_t)i * DMODEL * DINNER, h, h, DMODEL, DINNER);
        }
        rmsnorm_kernel<float><<<SEQL, 256, 0, stream>>>(h, nfw, xn, DMODEL);
        gemm_fb_kernel<0><<<dim3((VOCABSZ + 127) / 128, SEQL / 128), 256, 0, stream>>>(
            xn, emb, nullptr, out, VOCABSZ, DMODEL);
    }
}

// Round 6
// 1198.602 us; speedup vs baseline: 1.0773x; 1.0186x over previous
//
#include <hip/hip_runtime.h>
#include <cstdint>
#include <cstddef>

#define N_LAYER 4
#define VOCABSZ 50280
#define VOCABPAD 50304
#define DMODEL 768
#define DINNER 1536
#define DSTATE 16
#define DTRANK 48
#define SEQL 1024
#define HPSTRIDE (SEQL * DMODEL)

typedef __bf16 bf16x8 __attribute__((ext_vector_type(8)));
typedef unsigned short us8 __attribute__((ext_vector_type(8)));
typedef float f32x4 __attribute__((ext_vector_type(4)));

__device__ __forceinline__ unsigned short f2bf(float f) {
    unsigned int u = __builtin_bit_cast(unsigned int, f);
    u = (u + 0x7FFFu + ((u >> 16) & 1u)) >> 16;   // round-to-nearest-even
    return (unsigned short)u;
}

__device__ __forceinline__ void glds16(const unsigned short* g, unsigned short* l) {
    __builtin_amdgcn_global_load_lds(
        (const __attribute__((address_space(1))) void*)g,
        (__attribute__((address_space(3))) void*)l, 16, 0, 0);
}

__device__ __forceinline__ void cvt8(const float* s, unsigned short* d) {
    const float4* s4 = (const float4*)s;
    float4 a = s4[0], b = s4[1];
    us8 o = { f2bf(a.x), f2bf(a.y), f2bf(a.z), f2bf(a.w),
              f2bf(b.x), f2bf(b.y), f2bf(b.z), f2bf(b.w) };
    *(us8*)d = o;
}

// ---------------------------------------------------------------------------
// fp32 -> bf16 bulk convert (8 elems/thread)
// ---------------------------------------------------------------------------
__global__ __launch_bounds__(256) void cvt_bf16_kernel(
    const float* __restrict__ src, unsigned short* __restrict__ dst, int n8)
{
    int i = blockIdx.x * 256 + threadIdx.x;
    if (i >= n8) return;
    cvt8(src + (size_t)i * 8, dst + (size_t)i * 8);
}

// three fp32->bf16 conversions in ONE launch (emb, in_proj_w, out_proj_w)
__global__ __launch_bounds__(256) void cvt3_kernel(
    const float* __restrict__ s0, unsigned short* __restrict__ d0, int n0,
    const float* __restrict__ s1, unsigned short* __restrict__ d1, int n1,
    const float* __restrict__ s2, unsigned short* __restrict__ d2, int n2)
{
    int i = blockIdx.x * 256 + threadIdx.x;
    const float* s; unsigned short* d; int j = i;
    if (j < n0) { s = s0; d = d0; }
    else {
        j -= n0;
        if (j < n1) { s = s1; d = d1; }
        else {
            j -= n1;
            if (j >= n2) return;
            s = s2; d = d2;
        }
    }
    cvt8(s + (size_t)j * 8, d + (size_t)j * 8);
}

// ---------------------------------------------------------------------------
// x_proj_w (N_LAYER,80,1536) fp32 -> bf16, padded to 128 rows/layer (rows>=80
// zeroed so the 128-row GEMM staging reads defined data). 8 cols/thread.
// ---------------------------------------------------------------------------
__global__ __launch_bounds__(256) void cvt_xw_kernel(
    const float* __restrict__ xw, unsigned short* __restrict__ xwB)
{
    int g = blockIdx.x * 256 + threadIdx.x;
    if (g >= N_LAYER * 128 * 192) return;
    int row = g / 192;              // padded row 0 .. 4*128-1
    int c8  = g % 192;
    int layer = row >> 7;
    int r = row & 127;
    us8 o;
    if (r < 80) {
        const float4* s = (const float4*)(xw + ((size_t)(layer * 80 + r) * DINNER) + c8 * 8);
        float4 a = s[0], b = s[1];
        o = (us8){ f2bf(a.x), f2bf(a.y), f2bf(a.z), f2bf(a.w),
                   f2bf(b.x), f2bf(b.y), f2bf(b.z), f2bf(b.w) };
    } else {
        o = (us8){0, 0, 0, 0, 0, 0, 0, 0};
    }
    *(us8*)(xwB + (size_t)row * DINNER + c8 * 8) = o;
}

// ---------------------------------------------------------------------------
// bf16 NT GEMM core: C[m,n] = sum_{k in [0,Klen)} A[m,k]*B[n,k]
// (A/B may be pre-offset by the K-split base; Kstride = full row stride.)
// 128x128 tile, BK=32, 4 waves, 2-phase double-buffer (R5), both-sides
// bank-swizzle (R5: conflicts 9.66M -> 0), glds16 staging.
// ---------------------------------------------------------------------------
__device__ __forceinline__ void gemm_compute32(
    const unsigned short* sAbuf, const unsigned short* sBbuf,
    int wm, int wn, int frs, f32x4 (&acc)[4][4])
{
    bf16x8 af[4], bfr[4];
#pragma unroll
    for (int t = 0; t < 4; ++t) {
        af[t]  = __builtin_bit_cast(bf16x8, *(const us8*)&sAbuf[(wm + t * 16) * 32 + frs]);
        bfr[t] = __builtin_bit_cast(bf16x8, *(const us8*)&sBbuf[(wn + t * 16) * 32 + frs]);
    }
#pragma unroll
    for (int mt = 0; mt < 4; ++mt)
#pragma unroll
        for (int nt = 0; nt < 4; ++nt)
            acc[mt][nt] = __builtin_amdgcn_mfma_f32_16x16x32_bf16(
                af[mt], bfr[nt], acc[mt][nt], 0, 0, 0);
}

__device__ __forceinline__ void gemm_core(
    const unsigned short* __restrict__ A, const unsigned short* __restrict__ B,
    float* __restrict__ C, int N, int Kstride, int Klen, int bm, int bn)
{
    __shared__ unsigned short sA0[128 * 32];
    __shared__ unsigned short sA1[128 * 32];
    __shared__ unsigned short sB0[128 * 32];
    __shared__ unsigned short sB1[128 * 32];

    const int tid  = threadIdx.x;
    const int lane = tid & 63;
    const int wave = tid >> 6;
    const int wm = (wave & 1) * 64;
    const int wn = (wave >> 1) * 64;

    const int scol = ((tid & 3) ^ ((tid >> 3) & 3)) * 8;
    const unsigned short* Ag0 = A + (size_t)(bm + (tid >> 2)) * Kstride + scol;
    const unsigned short* Ag1 = Ag0 + (size_t)64 * Kstride;
    const unsigned short* Bg0 = B + (size_t)(bn + (tid >> 2)) * Kstride + scol;
    const unsigned short* Bg1 = Bg0 + (size_t)64 * Kstride;
    unsigned short* lA0a = sA0 + tid * 8;  unsigned short* lA0b = lA0a + 2048;
    unsigned short* lA1a = sA1 + tid * 8;  unsigned short* lA1b = lA1a + 2048;
    unsigned short* lB0a = sB0 + tid * 8;  unsigned short* lB0b = lB0a + 2048;
    unsigned short* lB1a = sB1 + tid * 8;  unsigned short* lB1b = lB1a + 2048;

    f32x4 acc[4][4];
#pragma unroll
    for (int i = 0; i < 4; ++i)
#pragma unroll
        for (int j = 0; j < 4; ++j) acc[i][j] = (f32x4){0.f, 0.f, 0.f, 0.f};

    const int frs = (lane & 15) * 32 + (((lane >> 4) ^ ((lane >> 1) & 3))) * 8;

    glds16(Ag0, lA0a); glds16(Ag1, lA0b);
    glds16(Bg0, lB0a); glds16(Bg1, lB0b);
    Ag0 += 32; Ag1 += 32; Bg0 += 32; Bg1 += 32;
    __syncthreads();

    for (int k0 = 0; k0 < Klen; k0 += 64) {
        glds16(Ag0, lA1a); glds16(Ag1, lA1b);
        glds16(Bg0, lB1a); glds16(Bg1, lB1b);
        Ag0 += 32; Ag1 += 32; Bg0 += 32; Bg1 += 32;
        gemm_compute32(sA0, sB0, wm, wn, frs, acc);
        __syncthreads();

        if (k0 + 64 < Klen) {
            glds16(Ag0, lA0a); glds16(Ag1, lA0b);
            glds16(Bg0, lB0a); glds16(Bg1, lB0b);
            Ag0 += 32; Ag1 += 32; Bg0 += 32; Bg1 += 32;
        }
        gemm_compute32(sA1, sB1, wm, wn, frs, acc);
        __syncthreads();
    }

    const int cn = lane & 15;
    const int cm = (lane >> 4) * 4;
#pragma unroll
    for (int mt = 0; mt < 4; ++mt) {
#pragma unroll
        for (int nt = 0; nt < 4; ++nt) {
            int n = bn + wn + nt * 16 + cn;
            if (n < N) {
#pragma unroll
                for (int r = 0; r < 4; ++r) {
                    int m = bm + wm + mt * 16 + cm + r;
                    C[(size_t)m * N + n] = acc[mt][nt][r];
                }
            }
        }
    }
}

// XCD-swizzled wrappers (grid%8==0): swz puts the 8 M-blocks of a B-panel on
// one XCD (R2-proven: FETCH 307->108 MB on logits).
__device__ __forceinline__ void swz_mn(int bid, int grid, int& bm, int& bn)
{
    int cpx = grid >> 3;
    int swz = (bid & 7) * cpx + (bid >> 3);
    bm = (swz & 7) << 7;
    bn = (swz >> 3) << 7;
}

__global__ __launch_bounds__(256) void gemm_in_kernel(
    const unsigned short* __restrict__ A, const unsigned short* __restrict__ B,
    float* __restrict__ C, int N, int K)
{ int bm, bn; swz_mn(blockIdx.x, gridDim.x, bm, bn); gemm_core(A, B, C, N, K, K, bm, bn); }

__global__ __launch_bounds__(256) void gemm_xproj_kernel(
    const unsigned short* __restrict__ A, const unsigned short* __restrict__ B,
    float* __restrict__ C, int N, int K)
{ int bm, bn; swz_mn(blockIdx.x, gridDim.x, bm, bn); gemm_core(A, B, C, N, K, K, bm, bn); }

__global__ __launch_bounds__(256) void gemm_logits_kernel(
    const unsigned short* __restrict__ A, const unsigned short* __restrict__ B,
    float* __restrict__ C, int N, int K)
{ int bm, bn; swz_mn(blockIdx.x, gridDim.x, bm, bn); gemm_core(A, B, C, N, K, K, bm, bn); }

// split-K x4 gemm_out: one 192-block launch; split s covers K [s*384,(s+1)*384),
// writes partial C into hp + s*HPSTRIDE. Residual+reduction happens in
// rmsnorm_acc_kernel (next layer). 4x parallelism vs the 48-block original.
__global__ __launch_bounds__(256) void gemm_outp_kernel(
    const unsigned short* __restrict__ A, const unsigned short* __restrict__ B,
    float* __restrict__ hp, int N, int Kstride, int Klen)
{
    int bid = blockIdx.x;
    int split = bid / 48;
    int r = bid - split * 48;
    int swz = (r & 7) * 6 + (r >> 3);        // bijective over 0..47
    int bm = (swz & 7) << 7;
    int bn = (swz >> 3) << 7;
    int kbase = split * Klen;
    gemm_core(A + kbase, B + kbase, hp + (size_t)split * HPSTRIDE,
              N, Kstride, Klen, bm, bn);
}

// ---------------------------------------------------------------------------
// fallback fp32 GEMM (R0 code, known-pass) for small-ws safety
// ---------------------------------------------------------------------------
template <int ADD>
__global__ __launch_bounds__(256) void gemm_fb_kernel(
    const float* __restrict__ A, const float* __restrict__ B,
    const float* __restrict__ ADDSRC, float* __restrict__ C,
    int N, int K)
{
    __shared__ unsigned short sA[128 * 40];
    __shared__ unsigned short sB[128 * 40];
    const int tid  = threadIdx.x;
    const int lane = tid & 63;
    const int wave = tid >> 6;
    const int wm = (wave & 1) * 64;
    const int wn = (wave >> 1) * 64;
    const int bm = blockIdx.y * 128;
    const int bn = blockIdx.x * 128;
    const int srow = tid >> 1;
    const int scol = (tid & 1) * 16;
    const float* Ap = A + (size_t)(bm + srow) * K + scol;
    const int brow  = bn + srow;
    const bool bvalid = brow < N;
    const float* Bp = B + (size_t)(bvalid ? brow : 0) * K + scol;
    f32x4 acc[4][4];
#pragma unroll
    for (int i = 0; i < 4; ++i)
#pragma unroll
        for (int j = 0; j < 4; ++j) acc[i][j] = (f32x4){0.f, 0.f, 0.f, 0.f};
    unsigned short* sAp = &sA[srow * 40 + scol];
    unsigned short* sBp = &sB[srow * 40 + scol];
    const int fr = (lane & 15) * 40 + (lane >> 4) * 8;
    for (int k0 = 0; k0 < K; k0 += 32) {
        float4 a0 = *(const float4*)(Ap + k0);
        float4 a1 = *(const float4*)(Ap + k0 + 4);
        float4 a2 = *(const float4*)(Ap + k0 + 8);
        float4 a3 = *(const float4*)(Ap + k0 + 12);
        float4 b0, b1, b2, b3;
        if (bvalid) {
            b0 = *(const float4*)(Bp + k0);
            b1 = *(const float4*)(Bp + k0 + 4);
            b2 = *(const float4*)(Bp + k0 + 8);
            b3 = *(const float4*)(Bp + k0 + 12);
        } else {
            b0 = make_float4(0.f, 0.f, 0.f, 0.f);
            b1 = b0; b2 = b0; b3 = b0;
        }
        __syncthreads();
        us8 va0 = { f2bf(a0.x), f2bf(a0.y), f2bf(a0.z), f2bf(a0.w),
                    f2bf(a1.x), f2bf(a1.y), f2bf(a1.z), f2bf(a1.w) };
        us8 va1 = { f2bf(a2.x), f2bf(a2.y), f2bf(a2.z), f2bf(a2.w),
                    f2bf(a3.x), f2bf(a3.y), f2bf(a3.z), f2bf(a3.w) };
        us8 vb0 = { f2bf(b0.x), f2bf(b0.y), f2bf(b0.z), f2bf(b0.w),
                    f2bf(b1.x), f2bf(b1.y), f2bf(b1.z), f2bf(b1.w) };
        us8 vb1 = { f2bf(b2.x), f2bf(b2.y), f2bf(b2.z), f2bf(b2.w),
                    f2bf(b3.x), f2bf(b3.y), f2bf(b3.z), f2bf(b3.w) };
        *(us8*)(sAp)     = va0;
        *(us8*)(sAp + 8) = va1;
        *(us8*)(sBp)     = vb0;
        *(us8*)(sBp + 8) = vb1;
        __syncthreads();
        bf16x8 af[4], bfr[4];
#pragma unroll
        for (int t = 0; t < 4; ++t) {
            af[t]  = __builtin_bit_cast(bf16x8, *(const us8*)&sA[wm * 40 + t * 640 + fr]);
            bfr[t] = __builtin_bit_cast(bf16x8, *(const us8*)&sB[wn * 40 + t * 640 + fr]);
        }
#pragma unroll
        for (int mt = 0; mt < 4; ++mt)
#pragma unroll
            for (int nt = 0; nt < 4; ++nt)
                acc[mt][nt] = __builtin_amdgcn_mfma_f32_16x16x32_bf16(
                    af[mt], bfr[nt], acc[mt][nt], 0, 0, 0);
    }
    const int cn = lane & 15;
    const int cm = (lane >> 4) * 4;
#pragma unroll
    for (int mt = 0; mt < 4; ++mt) {
#pragma unroll
        for (int nt = 0; nt < 4; ++nt) {
            int n = bn + wn + nt * 16 + cn;
            if (n < N) {
#pragma unroll
                for (int r = 0; r < 4; ++r) {
                    int m = bm + wm + mt * 16 + cm + r;
                    size_t idx = (size_t)m * N + n;
                    float v = acc[mt][nt][r];
                    if constexpr (ADD) v += ADDSRC[idx];
                    C[idx] = v;
                }
            }
        }
    }
}

// ---------------------------------------------------------------------------
__global__ __launch_bounds__(256) void embed_kernel(
    const int* __restrict__ ids, const float* __restrict__ emb, float* __restrict__ h)
{
    int l = blockIdx.x;
    int id = ids[l];
    const float* src = emb + (size_t)id * DMODEL;
    for (int d = threadIdx.x; d < DMODEL; d += 256) h[(size_t)l * DMODEL + d] = src[d];
}

template <typename OT>
__global__ __launch_bounds__(256) void rmsnorm_kernel(
    const float* __restrict__ x, const float* __restrict__ w,
    OT* __restrict__ out, int D)
{
    int l = blockIdx.x;
    const float* xr = x + (size_t)l * D;
    float ss = 0.f;
    for (int d = threadIdx.x; d < D; d += 256) { float v = xr[d]; ss += v * v; }
#pragma unroll
    for (int off = 32; off > 0; off >>= 1) ss += __shfl_down(ss, off, 64);
    __shared__ float red[4];
    __shared__ float invs;
    if ((threadIdx.x & 63) == 0) red[threadIdx.x >> 6] = ss;
    __syncthreads();
    if (threadIdx.x == 0)
        invs = rsqrtf((red[0] + red[1] + red[2] + red[3]) / (float)D + 1e-5f);
    __syncthreads();
    float inv = invs;
    for (int d = threadIdx.x; d < D; d += 256) {
        float v = xr[d] * inv * w[d];
        if constexpr (sizeof(OT) == 2) out[(size_t)l * D + d] = f2bf(v);
        else                           out[(size_t)l * D + d] = v;
    }
}

// accumulate 4 gemm_out K-split partials + residual into h, then rmsnorm -> bf16
__global__ __launch_bounds__(256) void rmsnorm_acc_kernel(
    float* __restrict__ h, const float* __restrict__ hp,
    const float* __restrict__ w, unsigned short* __restrict__ out)
{
    int l = blockIdx.x;
    const size_t base = (size_t)l * DMODEL;
    __shared__ float row[DMODEL];
    float ss = 0.f;
    for (int d = threadIdx.x; d < DMODEL; d += 256) {
        float v = h[base + d]
                + hp[base + d]
                + hp[base + d + (size_t)HPSTRIDE]
                + hp[base + d + (size_t)2 * HPSTRIDE]
                + hp[base + d + (size_t)3 * HPSTRIDE];
        row[d] = v;
        h[base + d] = v;
        ss += v * v;
    }
#pragma unroll
    for (int off = 32; off > 0; off >>= 1) ss += __shfl_down(ss, off, 64);
    __shared__ float red[4];
    __shared__ float invs;
    if ((threadIdx.x & 63) == 0) red[threadIdx.x >> 6] = ss;
    __syncthreads();
    if (threadIdx.x == 0)
        invs = rsqrtf((red[0] + red[1] + red[2] + red[3]) / (float)DMODEL + 1e-5f);
    __syncthreads();
    float inv = invs;
    for (int d = threadIdx.x; d < DMODEL; d += 256)
        out[base + d] = f2bf(row[d] * inv * w[d]);
}

// conv+silu; emits fp32 xc (scan) and bf16 xcB (xproj GEMM A-operand)
__global__ __launch_bounds__(256) void conv_silu_kernel(
    const float* __restrict__ xz, const float* __restrict__ cw,
    const float* __restrict__ cb, float* __restrict__ xc,
    unsigned short* __restrict__ xcB)
{
    int l = blockIdx.x / 6;
    int d = (blockIdx.x % 6) * 256 + threadIdx.x;
    float w0 = cw[d * 4], w1 = cw[d * 4 + 1], w2 = cw[d * 4 + 2], w3 = cw[d * 4 + 3];
    float acc = cb[d];
    if (l >= 3) acc += xz[(size_t)(l - 3) * 3072 + d] * w0;
    if (l >= 2) acc += xz[(size_t)(l - 2) * 3072 + d] * w1;
    if (l >= 1) acc += xz[(size_t)(l - 1) * 3072 + d] * w2;
    acc += xz[(size_t)l * 3072 + d] * w3;
    float sig = 1.f / (1.f + __expf(-acc));
    float v = acc * sig;
    size_t idx = (size_t)l * DINNER + d;
    xc[idx]  = v;
    xcB[idx] = f2bf(v);
}

// fallback-only fp32 xproj (latency-bound; main path uses gemm_xproj_kernel)
__global__ __launch_bounds__(256) void xproj_kernel(
    const float* __restrict__ xc, const float* __restrict__ xw, float* __restrict__ dbl)
{
    int l = blockIdx.x;
    __shared__ float sx[DINNER];
    for (int d = threadIdx.x; d < DINNER; d += 256) sx[d] = xc[(size_t)l * DINNER + d];
    __syncthreads();
    int wave = threadIdx.x >> 6, lane = threadIdx.x & 63;
    for (int e = wave * 20; e < wave * 20 + 20; ++e) {
        const float* wr = xw + (size_t)e * DINNER;
        float s = 0.f;
        for (int d = lane; d < DINNER; d += 64) s += sx[d] * wr[d];
#pragma unroll
        for (int off = 32; off > 0; off >>= 1) s += __shfl_down(s, off, 64);
        if (lane == 0) dbl[l * 80 + e] = s;
    }
}

// fallback-only dtproj (main path fuses this into scan_fused_kernel)
__global__ __launch_bounds__(256) void dtproj_kernel(
    const float* __restrict__ dbl, const float* __restrict__ dtw,
    const float* __restrict__ dtb, float* __restrict__ dt)
{
    int l = blockIdx.x / 6;
    int e = (blockIdx.x % 6) * 256 + threadIdx.x;
    __shared__ float sd[48];
    if (threadIdx.x < 48) sd[threadIdx.x] = dbl[l * 80 + threadIdx.x];
    __syncthreads();
    float a = dtb[e];
    const float4* wr = (const float4*)(dtw + (size_t)e * 48);
#pragma unroll
    for (int q = 0; q < 12; ++q) {
        float4 w4 = wr[q];
        a += sd[q * 4] * w4.x + sd[q * 4 + 1] * w4.y + sd[q * 4 + 2] * w4.z + sd[q * 4 + 3] * w4.w;
    }
    dt[(size_t)l * DINNER + e] = (a > 20.f) ? a : log1pf(__expf(a));
}

// fallback-only scan (reads precomputed dt)
template <typename OT>
__global__ __launch_bounds__(64) void scan_kernel(
    const float* __restrict__ dt, const float* __restrict__ dbl,
    const float* __restrict__ xc, const float* __restrict__ xz,
    const float* __restrict__ alog, const float* __restrict__ dpar,
    OT* __restrict__ yf)
{
    int d0 = blockIdx.x * 4;
    int lane = threadIdx.x;
    int n = lane & 15;
    int dloc = lane >> 4;
    int d = d0 + dloc;
    float A = -__expf(alog[d * 16 + n]);
    float Dq[4];
#pragma unroll
    for (int q = 0; q < 4; ++q) Dq[q] = dpar[d0 + q];

    __shared__ float sdt[64][4];
    __shared__ float sxc[64][4];
    __shared__ float sz[64][4];
    __shared__ float sB[64][16];
    __shared__ float sC[64][16];
    __shared__ float pp[4][64][17];

    float s = 0.f;
    for (int c0 = 0; c0 < SEQL; c0 += 64) {
        int l = c0 + lane;
        *(float4*)&sdt[lane][0] = *(const float4*)&dt[(size_t)l * DINNER + d0];
        *(float4*)&sxc[lane][0] = *(const float4*)&xc[(size_t)l * DINNER + d0];
        *(float4*)&sz[lane][0]  = *(const float4*)&xz[(size_t)l * 3072 + DINNER + d0];
#pragma unroll
        for (int q = 0; q < 4; ++q) {
            *(float4*)&sB[lane][q * 4] = *(const float4*)&dbl[l * 80 + 48 + q * 4];
            *(float4*)&sC[lane][q * 4] = *(const float4*)&dbl[l * 80 + 64 + q * 4];
        }
        __syncthreads();
#pragma unroll 4
        for (int j = 0; j < 64; ++j) {
            float dtv = sdt[j][dloc];
            float xv  = sxc[j][dloc];
            float a = __expf(dtv * A);
            s = fmaf(a, s, dtv * sB[j][n] * xv);
            pp[dloc][j][n] = s * sC[j][n];
        }
        __syncthreads();
#pragma unroll
        for (int q = 0; q < 4; ++q) {
            float accv = 0.f;
#pragma unroll
            for (int nn = 0; nn < 16; ++nn) accv += pp[q][lane][nn];
            float xv = sxc[lane][q];
            float zv = sz[lane][q];
            float sig = 1.f / (1.f + __expf(-zv));
            float v = (accv + xv * Dq[q]) * (zv * sig);
            if constexpr (sizeof(OT) == 2) yf[(size_t)(c0 + lane) * DINNER + d0 + q] = f2bf(v);
            else                           yf[(size_t)(c0 + lane) * DINNER + d0 + q] = v;
        }
        __syncthreads();
    }
}

// ---------------------------------------------------------------------------
// main-path scan with dtproj FUSED: dt[l,d] = softplus(dbl[l,0:48].dtw[d]+b)
// computed in-block (lane l holds its dbl row in 12 float4 regs; dtw rows for
// the block's 4 channels broadcast from LDS). Removes the dtproj launch and
// the 12 MB dt round-trip per layer.
// ---------------------------------------------------------------------------
__global__ __launch_bounds__(64) void scan_fused_kernel(
    const float* __restrict__ dbl, const float* __restrict__ xc,
    const float* __restrict__ xz, const float* __restrict__ dtw,
    const float* __restrict__ dtb, const float* __restrict__ alog,
    const float* __restrict__ dpar, unsigned short* __restrict__ yf)
{
    int d0 = blockIdx.x * 4;
    int lane = threadIdx.x;
    int n = lane & 15;
    int dloc = lane >> 4;
    int d = d0 + dloc;
    float A = -__expf(alog[d * 16 + n]);
    float Dq[4], dtbq[4];
#pragma unroll
    for (int q = 0; q < 4; ++q) { Dq[q] = dpar[d0 + q]; dtbq[q] = dtb[d0 + q]; }

    __shared__ float swt[4][48];     // dtw rows for the 4 channels
    for (int t = lane; t < 192; t += 64)
        swt[t / 48][t % 48] = dtw[(size_t)(d0 + t / 48) * 48 + t % 48];

    __shared__ float sdt[64][4];
    __shared__ float sxc[64][4];
    __shared__ float sz[64][4];
    __shared__ float sB[64][16];
    __shared__ float sC[64][16];
    __shared__ float pp[4][64][17];
    __syncthreads();                 // swt ready

    float s = 0.f;
    for (int c0 = 0; c0 < SEQL; c0 += 64) {
        int l = c0 + lane;
        *(float4*)&sxc[lane][0] = *(const float4*)&xc[(size_t)l * DINNER + d0];
        *(float4*)&sz[lane][0]  = *(const float4*)&xz[(size_t)l * 3072 + DINNER + d0];
        float4 db[12];
#pragma unroll
        for (int q4 = 0; q4 < 12; ++q4)
            db[q4] = *(const float4*)&dbl[l * 80 + q4 * 4];
#pragma unroll
        for (int q = 0; q < 4; ++q) {
            *(float4*)&sB[lane][q * 4] = *(const float4*)&dbl[l * 80 + 48 + q * 4];
            *(float4*)&sC[lane][q * 4] = *(const float4*)&dbl[l * 80 + 64 + q * 4];
        }
        // fused dtproj for this lane's l, all 4 channels
#pragma unroll
        for (int q = 0; q < 4; ++q) {
            float a = dtbq[q];
#pragma unroll
            for (int q4 = 0; q4 < 12; ++q4) {
                float4 w4 = *(const float4*)&swt[q][q4 * 4];
                a += db[q4].x * w4.x + db[q4].y * w4.y + db[q4].z * w4.z + db[q4].w * w4.w;
            }
            sdt[lane][q] = (a > 20.f) ? a : log1pf(__expf(a));
        }
        __syncthreads();
#pragma unroll 4
        for (int j = 0; j < 64; ++j) {
            float dtv = sdt[j][dloc];
            float xv  = sxc[j][dloc];
            float a = __expf(dtv * A);
            s = fmaf(a, s, dtv * sB[j][n] * xv);
            pp[dloc][j][n] = s * sC[j][n];
        }
        __syncthreads();
#pragma unroll
        for (int q = 0; q < 4; ++q) {
            float accv = 0.f;
#pragma unroll
            for (int nn = 0; nn < 16; ++nn) accv += pp[q][lane][nn];
            float xv = sxc[lane][q];
            float zv = sz[lane][q];
            float sig = 1.f / (1.f + __expf(-zv));
            float v = (accv + xv * Dq[q]) * (zv * sig);
            yf[(size_t)(c0 + lane) * DINNER + d0 + q] = f2bf(v);
        }
        __syncthreads();
    }
}

// ---------------------------------------------------------------------------
extern "C" void kernel_launch(void* const* d_in, const int* in_sizes, int n_in,
                              void* d_out, int out_size, void* d_ws, size_t ws_size,
                              hipStream_t stream)
{
    const int*   ids  = (const int*)d_in[0];
    const float* emb  = (const float*)d_in[1];
    const float* inw  = (const float*)d_in[2];
    const float* cw   = (const float*)d_in[3];
    const float* cb   = (const float*)d_in[4];
    const float* xw   = (const float*)d_in[5];
    const float* dtw  = (const float*)d_in[6];
    const float* dtb  = (const float*)d_in[7];
    const float* alog = (const float*)d_in[8];
    const float* dpar = (const float*)d_in[9];
    const float* ow   = (const float*)d_in[10];
    const float* nw   = (const float*)d_in[11];
    const float* nfw  = (const float*)d_in[12];
    float* out = (float*)d_out;

    const size_t MAIN_WS = 138936320ull;

    if (ws_size >= MAIN_WS) {
        char* p = (char*)d_ws;
        float* h    = (float*)p;                 p += (size_t)SEQL * DMODEL * 4;
        float* xz   = (float*)p;                 p += (size_t)SEQL * 3072 * 4;
        float* xc   = (float*)p;                 p += (size_t)SEQL * DINNER * 4;
        float* dbl  = (float*)p;                 p += (size_t)SEQL * 80 * 4;
        float* dt_unused = (float*)p;            p += (size_t)SEQL * DINNER * 4;
        unsigned short* xnB  = (unsigned short*)p; p += (size_t)SEQL * DMODEL * 2;
        unsigned short* yfB  = (unsigned short*)p; p += (size_t)SEQL * DINNER * 2;
        unsigned short* embB = (unsigned short*)p; p += (size_t)VOCABPAD * DMODEL * 2;
        unsigned short* inwB = (unsigned short*)p; p += (size_t)N_LAYER * 3072 * DMODEL * 2;
        unsigned short* owB  = (unsigned short*)p; p += (size_t)N_LAYER * DMODEL * DINNER * 2;
        (void)dt_unused;

        // scratch in the (write-only-at-end) logits output buffer:
        // xwB 1.5MB | xcB 3MB | hp 12MB (4 gemm_out K-split partials).
        // All consumed before gemm_logits writes out. No MAIN_WS growth.
        unsigned short* xwB = (unsigned short*)out;
        unsigned short* xcB = xwB + (size_t)N_LAYER * 128 * DINNER;
        float* hp = (float*)(xcB + (size_t)SEQL * DINNER);

        const int n0 = VOCABSZ * DMODEL / 8;
        const int n1 = N_LAYER * 3072 * DMODEL / 8;
        const int n2 = N_LAYER * DMODEL * DINNER / 8;
        cvt3_kernel<<<(n0 + n1 + n2 + 255) / 256, 256, 0, stream>>>(
            emb, embB, n0, inw, inwB, n1, ow, owB, n2);
        cvt_xw_kernel<<<(N_LAYER * 128 * 192 + 255) / 256, 256, 0, stream>>>(xw, xwB);

        embed_kernel<<<SEQL, 256, 0, stream>>>(ids, emb, h);

        for (int i = 0; i < N_LAYER; ++i) {
            if (i == 0)
                rmsnorm_kernel<unsigned short><<<SEQL, 256, 0, stream>>>(
                    h, nw, xnB, DMODEL);
            else
                rmsnorm_acc_kernel<<<SEQL, 256, 0, stream>>>(
                    h, hp, nw + (size_t)i * DMODEL, xnB);
            gemm_in_kernel<<<8 * (3072 / 128), 256, 0, stream>>>(
                xnB, inwB + (size_t)i * 3072 * DMODEL, xz, 3072, DMODEL);
            conv_silu_kernel<<<SEQL * 6, 256, 0, stream>>>(
                xz, cw + (size_t)i * DINNER * 4, cb + (size_t)i * DINNER, xc, xcB);
            gemm_xproj_kernel<<<8, 256, 0, stream>>>(
                xcB, xwB + (size_t)i * 128 * DINNER, dbl, 80, DINNER);
            scan_fused_kernel<<<DINNER / 4, 64, 0, stream>>>(
                dbl, xc, xz, dtw + (size_t)i * DINNER * DTRANK,
                dtb + (size_t)i * DINNER, alog + (size_t)i * DINNER * DSTATE,
                dpar + (size_t)i * DINNER, yfB);
            gemm_outp_kernel<<<4 * 48, 256, 0, stream>>>(
                yfB, owB + (size_t)i * DMODEL * DINNER, hp, DMODEL, DINNER, DINNER / 4);
        }

        rmsnorm_acc_kernel<<<SEQL, 256, 0, stream>>>(h, hp, nfw, xnB);
        gemm_logits_kernel<<<8 * ((VOCABSZ + 127) / 128), 256, 0, stream>>>(
            xnB, embB, out, VOCABSZ, DMODEL);
    } else {
        // fallback: R0 fp32 path (ws >= 38 MB verified)
        float* h   = (float*)d_ws;
        float* xn  = h  + (size_t)SEQL * DMODEL;
        float* xz  = xn + (size_t)SEQL * DMODEL;
        float* xc  = xz + (size_t)SEQL * 3072;
        float* dbl = xc + (size_t)SEQL * DINNER;
        float* dt  = dbl + (size_t)SEQL * 80;
        float* yf  = dt + (size_t)SEQL * DINNER;
        unsigned short* xcB = (unsigned short*)out;   // scratch, overwritten at end

        embed_kernel<<<SEQL, 256, 0, stream>>>(ids, emb, h);
        for (int i = 0; i < N_LAYER; ++i) {
            rmsnorm_kernel<float><<<SEQL, 256, 0, stream>>>(h, nw + (size_t)i * DMODEL, xn, DMODEL);
            gemm_fb_kernel<0><<<dim3(3072 / 128, SEQL / 128), 256, 0, stream>>>(
                xn, inw + (size_t)i * 3072 * DMODEL, nullptr, xz, 3072, DMODEL);
            conv_silu_kernel<<<SEQL * 6, 256, 0, stream>>>(
                xz, cw + (size_t)i * DINNER * 4, cb + (size_t)i * DINNER, xc, xcB);
            xproj_kernel<<<SEQL, 256, 0, stream>>>(xc, xw + (size_t)i * 80 * DINNER, dbl);
            dtproj_kernel<<<SEQL * 6, 256, 0, stream>>>(
                dbl, dtw + (size_t)i * DINNER * DTRANK, dtb + (size_t)i * DINNER, dt);
            scan_kernel<float><<<DINNER / 4, 64, 0, stream>>>(
                dt, dbl, xc, xz, alog + (size_t)i * DINNER * DSTATE, dpar + (size_t)i * DINNER, yf);
            gemm_fb_kernel<1><<<dim3(DMODEL / 128, SEQL / 128), 256, 0, stream>>>(
                yf, ow + (size_t)i * DMODEL * DINNER, h, h, DMODEL, DINNER);
        }
        rmsnorm_kernel<float><<<SEQL, 256, 0, stream>>>(h, nfw, xn, DMODEL);
        gemm_fb_kernel<0><<<dim3((VOCABSZ + 127) / 128, SEQL / 128), 256, 0, stream>>>(
            xn, emb, nullptr, out, VOCABSZ, DMODEL);
    }
}

// Round 7
// 1105.375 us; speedup vs baseline: 1.1682x; 1.0843x over previous
//
#include <hip/hip_runtime.h>
#include <cstdint>
#include <cstddef>

#define N_LAYER 4
#define VOCABSZ 50280
#define VOCABPAD 50304
#define DMODEL 768
#define DINNER 1536
#define DSTATE 16
#define DTRANK 48
#define SEQL 1024
#define HPSTRIDE (SEQL * DMODEL)
#define XPSTRIDE (SEQL * 80)

typedef __bf16 bf16x8 __attribute__((ext_vector_type(8)));
typedef unsigned short us8 __attribute__((ext_vector_type(8)));
typedef float f32x4 __attribute__((ext_vector_type(4)));

__device__ __forceinline__ unsigned short f2bf(float f) {
    unsigned int u = __builtin_bit_cast(unsigned int, f);
    u = (u + 0x7FFFu + ((u >> 16) & 1u)) >> 16;   // round-to-nearest-even
    return (unsigned short)u;
}

__device__ __forceinline__ void glds16(const unsigned short* g, unsigned short* l) {
    __builtin_amdgcn_global_load_lds(
        (const __attribute__((address_space(1))) void*)g,
        (__attribute__((address_space(3))) void*)l, 16, 0, 0);
}

__device__ __forceinline__ void cvt8(const float* s, unsigned short* d) {
    const float4* s4 = (const float4*)s;
    float4 a = s4[0], b = s4[1];
    us8 o = { f2bf(a.x), f2bf(a.y), f2bf(a.z), f2bf(a.w),
              f2bf(b.x), f2bf(b.y), f2bf(b.z), f2bf(b.w) };
    *(us8*)d = o;
}

// ---------------------------------------------------------------------------
// fp32 -> bf16 bulk convert (8 elems/thread)
// ---------------------------------------------------------------------------
__global__ __launch_bounds__(256) void cvt_bf16_kernel(
    const float* __restrict__ src, unsigned short* __restrict__ dst, int n8)
{
    int i = blockIdx.x * 256 + threadIdx.x;
    if (i >= n8) return;
    cvt8(src + (size_t)i * 8, dst + (size_t)i * 8);
}

// three fp32->bf16 conversions in ONE launch (emb, in_proj_w, out_proj_w)
__global__ __launch_bounds__(256) void cvt3_kernel(
    const float* __restrict__ s0, unsigned short* __restrict__ d0, int n0,
    const float* __restrict__ s1, unsigned short* __restrict__ d1, int n1,
    const float* __restrict__ s2, unsigned short* __restrict__ d2, int n2)
{
    int i = blockIdx.x * 256 + threadIdx.x;
    const float* s; unsigned short* d; int j = i;
    if (j < n0) { s = s0; d = d0; }
    else {
        j -= n0;
        if (j < n1) { s = s1; d = d1; }
        else {
            j -= n1;
            if (j >= n2) return;
            s = s2; d = d2;
        }
    }
    cvt8(s + (size_t)j * 8, d + (size_t)j * 8);
}

// ---------------------------------------------------------------------------
// x_proj_w (N_LAYER,80,1536) fp32 -> bf16, padded to 128 rows/layer (rows>=80
// zeroed so the 128-row GEMM staging reads defined data). 8 cols/thread.
// ---------------------------------------------------------------------------
__global__ __launch_bounds__(256) void cvt_xw_kernel(
    const float* __restrict__ xw, unsigned short* __restrict__ xwB)
{
    int g = blockIdx.x * 256 + threadIdx.x;
    if (g >= N_LAYER * 128 * 192) return;
    int row = g / 192;              // padded row 0 .. 4*128-1
    int c8  = g % 192;
    int layer = row >> 7;
    int r = row & 127;
    us8 o;
    if (r < 80) {
        const float4* s = (const float4*)(xw + ((size_t)(layer * 80 + r) * DINNER) + c8 * 8);
        float4 a = s[0], b = s[1];
        o = (us8){ f2bf(a.x), f2bf(a.y), f2bf(a.z), f2bf(a.w),
                   f2bf(b.x), f2bf(b.y), f2bf(b.z), f2bf(b.w) };
    } else {
        o = (us8){0, 0, 0, 0, 0, 0, 0, 0};
    }
    *(us8*)(xwB + (size_t)row * DINNER + c8 * 8) = o;
}

// ---------------------------------------------------------------------------
// shared MFMA compute for 128x128 tile fragments
// ---------------------------------------------------------------------------
__device__ __forceinline__ void gemm_compute32(
    const unsigned short* sAbuf, const unsigned short* sBbuf,
    int wm, int wn, int frs, f32x4 (&acc)[4][4])
{
    bf16x8 af[4], bfr[4];
#pragma unroll
    for (int t = 0; t < 4; ++t) {
        af[t]  = __builtin_bit_cast(bf16x8, *(const us8*)&sAbuf[(wm + t * 16) * 32 + frs]);
        bfr[t] = __builtin_bit_cast(bf16x8, *(const us8*)&sBbuf[(wn + t * 16) * 32 + frs]);
    }
#pragma unroll
    for (int mt = 0; mt < 4; ++mt)
#pragma unroll
        for (int nt = 0; nt < 4; ++nt)
            acc[mt][nt] = __builtin_amdgcn_mfma_f32_16x16x32_bf16(
                af[mt], bfr[nt], acc[mt][nt], 0, 0, 0);
}

// ---------------------------------------------------------------------------
// 2-phase double-buffered core (R5): used by per-layer GEMMs where it
// measured -80us aggregate. Both-sides bank-swizzle (conflicts 9.66M -> 0).
// ---------------------------------------------------------------------------
__device__ __forceinline__ void gemm_core(
    const unsigned short* __restrict__ A, const unsigned short* __restrict__ B,
    float* __restrict__ C, int N, int Kstride, int Klen, int bm, int bn)
{
    __shared__ unsigned short sA0[128 * 32];
    __shared__ unsigned short sA1[128 * 32];
    __shared__ unsigned short sB0[128 * 32];
    __shared__ unsigned short sB1[128 * 32];

    const int tid  = threadIdx.x;
    const int lane = tid & 63;
    const int wave = tid >> 6;
    const int wm = (wave & 1) * 64;
    const int wn = (wave >> 1) * 64;

    const int scol = ((tid & 3) ^ ((tid >> 3) & 3)) * 8;
    const unsigned short* Ag0 = A + (size_t)(bm + (tid >> 2)) * Kstride + scol;
    const unsigned short* Ag1 = Ag0 + (size_t)64 * Kstride;
    const unsigned short* Bg0 = B + (size_t)(bn + (tid >> 2)) * Kstride + scol;
    const unsigned short* Bg1 = Bg0 + (size_t)64 * Kstride;
    unsigned short* lA0a = sA0 + tid * 8;  unsigned short* lA0b = lA0a + 2048;
    unsigned short* lA1a = sA1 + tid * 8;  unsigned short* lA1b = lA1a + 2048;
    unsigned short* lB0a = sB0 + tid * 8;  unsigned short* lB0b = lB0a + 2048;
    unsigned short* lB1a = sB1 + tid * 8;  unsigned short* lB1b = lB1a + 2048;

    f32x4 acc[4][4];
#pragma unroll
    for (int i = 0; i < 4; ++i)
#pragma unroll
        for (int j = 0; j < 4; ++j) acc[i][j] = (f32x4){0.f, 0.f, 0.f, 0.f};

    const int frs = (lane & 15) * 32 + (((lane >> 4) ^ ((lane >> 1) & 3))) * 8;

    glds16(Ag0, lA0a); glds16(Ag1, lA0b);
    glds16(Bg0, lB0a); glds16(Bg1, lB0b);
    Ag0 += 32; Ag1 += 32; Bg0 += 32; Bg1 += 32;
    __syncthreads();

    for (int k0 = 0; k0 < Klen; k0 += 64) {
        glds16(Ag0, lA1a); glds16(Ag1, lA1b);
        glds16(Bg0, lB1a); glds16(Bg1, lB1b);
        Ag0 += 32; Ag1 += 32; Bg0 += 32; Bg1 += 32;
        gemm_compute32(sA0, sB0, wm, wn, frs, acc);
        __syncthreads();

        if (k0 + 64 < Klen) {
            glds16(Ag0, lA0a); glds16(Ag1, lA0b);
            glds16(Bg0, lB0a); glds16(Bg1, lB0b);
            Ag0 += 32; Ag1 += 32; Bg0 += 32; Bg1 += 32;
        }
        gemm_compute32(sA1, sB1, wm, wn, frs, acc);
        __syncthreads();
    }

    const int cn = lane & 15;
    const int cm = (lane >> 4) * 4;
#pragma unroll
    for (int mt = 0; mt < 4; ++mt) {
#pragma unroll
        for (int nt = 0; nt < 4; ++nt) {
            int n = bn + wn + nt * 16 + cn;
            if (n < N) {
#pragma unroll
                for (int r = 0; r < 4; ++r) {
                    int m = bm + wm + mt * 16 + cm + r;
                    C[(size_t)m * N + n] = acc[mt][nt][r];
                }
            }
        }
    }
}

// XCD-swizzled mapping (grid%8==0)
__device__ __forceinline__ void swz_mn(int bid, int grid, int& bm, int& bn)
{
    int cpx = grid >> 3;
    int swz = (bid & 7) * cpx + (bid >> 3);
    bm = (swz & 7) << 7;
    bn = (swz >> 3) << 7;
}

__global__ __launch_bounds__(256) void gemm_in_kernel(
    const unsigned short* __restrict__ A, const unsigned short* __restrict__ B,
    float* __restrict__ C, int N, int K)
{ int bm, bn; swz_mn(blockIdx.x, gridDim.x, bm, bn); gemm_core(A, B, C, N, K, K, bm, bn); }

// split-K x8 xproj: grid 64 = 8 splits x 8 m-tiles; Klen=192 (3 iters/block).
// Partials into xpp[split]; reduced by xred_kernel. Replaces the grid=8
// latency-bound xproj (24 serial iters, 97% GPU idle).
__global__ __launch_bounds__(256) void gemm_xprojk_kernel(
    const unsigned short* __restrict__ A, const unsigned short* __restrict__ B,
    float* __restrict__ xpp)
{
    int split = blockIdx.x >> 3;
    int bm = (blockIdx.x & 7) << 7;
    int kbase = split * 192;
    gemm_core(A + kbase, B + kbase, xpp + (size_t)split * XPSTRIDE,
              80, DINNER, 192, bm, 0);
}

__global__ __launch_bounds__(256) void xred_kernel(
    const float* __restrict__ xpp, float* __restrict__ dbl)
{
    int i = blockIdx.x * 256 + threadIdx.x;     // float4 index
    if (i >= XPSTRIDE / 4) return;
    const f32x4* p = (const f32x4*)xpp + i;
    f32x4 s = p[0];
#pragma unroll
    for (int k = 1; k < 8; ++k) s += p[(size_t)k * (XPSTRIDE / 4)];
    ((f32x4*)dbl)[i] = s;
}

// split-K x4 gemm_out (R6): one 192-block launch; partials into hp[split];
// reduced+residual'd by rmsnorm_acc_kernel.
__global__ __launch_bounds__(256) void gemm_outp_kernel(
    const unsigned short* __restrict__ A, const unsigned short* __restrict__ B,
    float* __restrict__ hp, int N, int Kstride, int Klen)
{
    int bid = blockIdx.x;
    int split = bid / 48;
    int r = bid - split * 48;
    int swz = (r & 7) * 6 + (r >> 3);        // bijective over 0..47
    int bm = (swz & 7) << 7;
    int bn = (swz >> 3) << 7;
    int kbase = split * Klen;
    gemm_core(A + kbase, B + kbase, hp + (size_t)split * HPSTRIDE,
              N, Kstride, Klen, bm, bn);
}

// ---------------------------------------------------------------------------
// logits GEMM: 1-phase 16KB body (R4-best: 165us @ occ 27%; the 2-phase 32KB
// variant dropped occupancy to 18% and regressed to 176 -- T2/T3 regime-gated
// null at this structure). Keeps the free swizzle (conflicts 0) + XCD swizzle.
// ---------------------------------------------------------------------------
__global__ __launch_bounds__(256) void gemm_logits_kernel(
    const unsigned short* __restrict__ A, const unsigned short* __restrict__ B,
    float* __restrict__ C, int N, int K)
{
    __shared__ unsigned short sA[128 * 32];
    __shared__ unsigned short sB[128 * 32];

    const int tid  = threadIdx.x;
    const int lane = tid & 63;
    const int wave = tid >> 6;
    const int wm = (wave & 1) * 64;
    const int wn = (wave >> 1) * 64;
    int bm, bn;
    swz_mn(blockIdx.x, gridDim.x, bm, bn);

    const int scol = ((tid & 3) ^ ((tid >> 3) & 3)) * 8;
    const unsigned short* Ag0 = A + (size_t)(bm + (tid >> 2)) * K + scol;
    const unsigned short* Ag1 = Ag0 + (size_t)64 * K;
    const unsigned short* Bg0 = B + (size_t)(bn + (tid >> 2)) * K + scol;
    const unsigned short* Bg1 = Bg0 + (size_t)64 * K;
    unsigned short* lA0 = sA + tid * 8;
    unsigned short* lA1 = lA0 + 2048;
    unsigned short* lB0 = sB + tid * 8;
    unsigned short* lB1 = lB0 + 2048;

    f32x4 acc[4][4];
#pragma unroll
    for (int i = 0; i < 4; ++i)
#pragma unroll
        for (int j = 0; j < 4; ++j) acc[i][j] = (f32x4){0.f, 0.f, 0.f, 0.f};

    const int frs = (lane & 15) * 32 + (((lane >> 4) ^ ((lane >> 1) & 3))) * 8;

    for (int k0 = 0; k0 < K; k0 += 32) {
        __syncthreads();
        glds16(Ag0, lA0);
        glds16(Ag1, lA1);
        glds16(Bg0, lB0);
        glds16(Bg1, lB1);
        Ag0 += 32; Ag1 += 32; Bg0 += 32; Bg1 += 32;
        __syncthreads();
        gemm_compute32(sA, sB, wm, wn, frs, acc);
    }

    const int cn = lane & 15;
    const int cm = (lane >> 4) * 4;
#pragma unroll
    for (int mt = 0; mt < 4; ++mt) {
#pragma unroll
        for (int nt = 0; nt < 4; ++nt) {
            int n = bn + wn + nt * 16 + cn;
            if (n < N) {
#pragma unroll
                for (int r = 0; r < 4; ++r) {
                    int m = bm + wm + mt * 16 + cm + r;
                    C[(size_t)m * N + n] = acc[mt][nt][r];
                }
            }
        }
    }
}

// ---------------------------------------------------------------------------
// fallback fp32 GEMM (R0 code, known-pass) for small-ws safety
// ---------------------------------------------------------------------------
template <int ADD>
__global__ __launch_bounds__(256) void gemm_fb_kernel(
    const float* __restrict__ A, const float* __restrict__ B,
    const float* __restrict__ ADDSRC, float* __restrict__ C,
    int N, int K)
{
    __shared__ unsigned short sA[128 * 40];
    __shared__ unsigned short sB[128 * 40];
    const int tid  = threadIdx.x;
    const int lane = tid & 63;
    const int wave = tid >> 6;
    const int wm = (wave & 1) * 64;
    const int wn = (wave >> 1) * 64;
    const int bm = blockIdx.y * 128;
    const int bn = blockIdx.x * 128;
    const int srow = tid >> 1;
    const int scol = (tid & 1) * 16;
    const float* Ap = A + (size_t)(bm + srow) * K + scol;
    const int brow  = bn + srow;
    const bool bvalid = brow < N;
    const float* Bp = B + (size_t)(bvalid ? brow : 0) * K + scol;
    f32x4 acc[4][4];
#pragma unroll
    for (int i = 0; i < 4; ++i)
#pragma unroll
        for (int j = 0; j < 4; ++j) acc[i][j] = (f32x4){0.f, 0.f, 0.f, 0.f};
    unsigned short* sAp = &sA[srow * 40 + scol];
    unsigned short* sBp = &sB[srow * 40 + scol];
    const int fr = (lane & 15) * 40 + (lane >> 4) * 8;
    for (int k0 = 0; k0 < K; k0 += 32) {
        float4 a0 = *(const float4*)(Ap + k0);
        float4 a1 = *(const float4*)(Ap + k0 + 4);
        float4 a2 = *(const float4*)(Ap + k0 + 8);
        float4 a3 = *(const float4*)(Ap + k0 + 12);
        float4 b0, b1, b2, b3;
        if (bvalid) {
            b0 = *(const float4*)(Bp + k0);
            b1 = *(const float4*)(Bp + k0 + 4);
            b2 = *(const float4*)(Bp + k0 + 8);
            b3 = *(const float4*)(Bp + k0 + 12);
        } else {
            b0 = make_float4(0.f, 0.f, 0.f, 0.f);
            b1 = b0; b2 = b0; b3 = b0;
        }
        __syncthreads();
        us8 va0 = { f2bf(a0.x), f2bf(a0.y), f2bf(a0.z), f2bf(a0.w),
                    f2bf(a1.x), f2bf(a1.y), f2bf(a1.z), f2bf(a1.w) };
        us8 va1 = { f2bf(a2.x), f2bf(a2.y), f2bf(a2.z), f2bf(a2.w),
                    f2bf(a3.x), f2bf(a3.y), f2bf(a3.z), f2bf(a3.w) };
        us8 vb0 = { f2bf(b0.x), f2bf(b0.y), f2bf(b0.z), f2bf(b0.w),
                    f2bf(b1.x), f2bf(b1.y), f2bf(b1.z), f2bf(b1.w) };
        us8 vb1 = { f2bf(b2.x), f2bf(b2.y), f2bf(b2.z), f2bf(b2.w),
                    f2bf(b3.x), f2bf(b3.y), f2bf(b3.z), f2bf(b3.w) };
        *(us8*)(sAp)     = va0;
        *(us8*)(sAp + 8) = va1;
        *(us8*)(sBp)     = vb0;
        *(us8*)(sBp + 8) = vb1;
        __syncthreads();
        bf16x8 af[4], bfr[4];
#pragma unroll
        for (int t = 0; t < 4; ++t) {
            af[t]  = __builtin_bit_cast(bf16x8, *(const us8*)&sA[wm * 40 + t * 640 + fr]);
            bfr[t] = __builtin_bit_cast(bf16x8, *(const us8*)&sB[wn * 40 + t * 640 + fr]);
        }
#pragma unroll
        for (int mt = 0; mt < 4; ++mt)
#pragma unroll
            for (int nt = 0; nt < 4; ++nt)
                acc[mt][nt] = __builtin_amdgcn_mfma_f32_16x16x32_bf16(
                    af[mt], bfr[nt], acc[mt][nt], 0, 0, 0);
    }
    const int cn = lane & 15;
    const int cm = (lane >> 4) * 4;
#pragma unroll
    for (int mt = 0; mt < 4; ++mt) {
#pragma unroll
        for (int nt = 0; nt < 4; ++nt) {
            int n = bn + wn + nt * 16 + cn;
            if (n < N) {
#pragma unroll
                for (int r = 0; r < 4; ++r) {
                    int m = bm + wm + mt * 16 + cm + r;
                    size_t idx = (size_t)m * N + n;
                    float v = acc[mt][nt][r];
                    if constexpr (ADD) v += ADDSRC[idx];
                    C[idx] = v;
                }
            }
        }
    }
}

// ---------------------------------------------------------------------------
__global__ __launch_bounds__(256) void embed_kernel(
    const int* __restrict__ ids, const float* __restrict__ emb, float* __restrict__ h)
{
    int l = blockIdx.x;
    int id = ids[l];
    const float* src = emb + (size_t)id * DMODEL;
    for (int d = threadIdx.x; d < DMODEL; d += 256) h[(size_t)l * DMODEL + d] = src[d];
}

template <typename OT>
__global__ __launch_bounds__(256) void rmsnorm_kernel(
    const float* __restrict__ x, const float* __restrict__ w,
    OT* __restrict__ out, int D)
{
    int l = blockIdx.x;
    const float* xr = x + (size_t)l * D;
    float ss = 0.f;
    for (int d = threadIdx.x; d < D; d += 256) { float v = xr[d]; ss += v * v; }
#pragma unroll
    for (int off = 32; off > 0; off >>= 1) ss += __shfl_down(ss, off, 64);
    __shared__ float red[4];
    __shared__ float invs;
    if ((threadIdx.x & 63) == 0) red[threadIdx.x >> 6] = ss;
    __syncthreads();
    if (threadIdx.x == 0)
        invs = rsqrtf((red[0] + red[1] + red[2] + red[3]) / (float)D + 1e-5f);
    __syncthreads();
    float inv = invs;
    for (int d = threadIdx.x; d < D; d += 256) {
        float v = xr[d] * inv * w[d];
        if constexpr (sizeof(OT) == 2) out[(size_t)l * D + d] = f2bf(v);
        else                           out[(size_t)l * D + d] = v;
    }
}

// accumulate 4 gemm_out K-split partials + residual into h, then rmsnorm -> bf16
__global__ __launch_bounds__(256) void rmsnorm_acc_kernel(
    float* __restrict__ h, const float* __restrict__ hp,
    const float* __restrict__ w, unsigned short* __restrict__ out)
{
    int l = blockIdx.x;
    const size_t base = (size_t)l * DMODEL;
    __shared__ float row[DMODEL];
    float ss = 0.f;
    for (int d = threadIdx.x; d < DMODEL; d += 256) {
        float v = h[base + d]
                + hp[base + d]
                + hp[base + d + (size_t)HPSTRIDE]
                + hp[base + d + (size_t)2 * HPSTRIDE]
                + hp[base + d + (size_t)3 * HPSTRIDE];
        row[d] = v;
        h[base + d] = v;
        ss += v * v;
    }
#pragma unroll
    for (int off = 32; off > 0; off >>= 1) ss += __shfl_down(ss, off, 64);
    __shared__ float red[4];
    __shared__ float invs;
    if ((threadIdx.x & 63) == 0) red[threadIdx.x >> 6] = ss;
    __syncthreads();
    if (threadIdx.x == 0)
        invs = rsqrtf((red[0] + red[1] + red[2] + red[3]) / (float)DMODEL + 1e-5f);
    __syncthreads();
    float inv = invs;
    for (int d = threadIdx.x; d < DMODEL; d += 256)
        out[base + d] = f2bf(row[d] * inv * w[d]);
}

// conv+silu; emits fp32 xc (scan) and bf16 xcB (xproj GEMM A-operand)
__global__ __launch_bounds__(256) void conv_silu_kernel(
    const float* __restrict__ xz, const float* __restrict__ cw,
    const float* __restrict__ cb, float* __restrict__ xc,
    unsigned short* __restrict__ xcB)
{
    int l = blockIdx.x / 6;
    int d = (blockIdx.x % 6) * 256 + threadIdx.x;
    float w0 = cw[d * 4], w1 = cw[d * 4 + 1], w2 = cw[d * 4 + 2], w3 = cw[d * 4 + 3];
    float acc = cb[d];
    if (l >= 3) acc += xz[(size_t)(l - 3) * 3072 + d] * w0;
    if (l >= 2) acc += xz[(size_t)(l - 2) * 3072 + d] * w1;
    if (l >= 1) acc += xz[(size_t)(l - 1) * 3072 + d] * w2;
    acc += xz[(size_t)l * 3072 + d] * w3;
    float sig = 1.f / (1.f + __expf(-acc));
    float v = acc * sig;
    size_t idx = (size_t)l * DINNER + d;
    xc[idx]  = v;
    xcB[idx] = f2bf(v);
}

// fallback-only fp32 xproj
__global__ __launch_bounds__(256) void xproj_kernel(
    const float* __restrict__ xc, const float* __restrict__ xw, float* __restrict__ dbl)
{
    int l = blockIdx.x;
    __shared__ float sx[DINNER];
    for (int d = threadIdx.x; d < DINNER; d += 256) sx[d] = xc[(size_t)l * DINNER + d];
    __syncthreads();
    int wave = threadIdx.x >> 6, lane = threadIdx.x & 63;
    for (int e = wave * 20; e < wave * 20 + 20; ++e) {
        const float* wr = xw + (size_t)e * DINNER;
        float s = 0.f;
        for (int d = lane; d < DINNER; d += 64) s += sx[d] * wr[d];
#pragma unroll
        for (int off = 32; off > 0; off >>= 1) s += __shfl_down(s, off, 64);
        if (lane == 0) dbl[l * 80 + e] = s;
    }
}

// fallback-only dtproj
__global__ __launch_bounds__(256) void dtproj_kernel(
    const float* __restrict__ dbl, const float* __restrict__ dtw,
    const float* __restrict__ dtb, float* __restrict__ dt)
{
    int l = blockIdx.x / 6;
    int e = (blockIdx.x % 6) * 256 + threadIdx.x;
    __shared__ float sd[48];
    if (threadIdx.x < 48) sd[threadIdx.x] = dbl[l * 80 + threadIdx.x];
    __syncthreads();
    float a = dtb[e];
    const float4* wr = (const float4*)(dtw + (size_t)e * 48);
#pragma unroll
    for (int q = 0; q < 12; ++q) {
        float4 w4 = wr[q];
        a += sd[q * 4] * w4.x + sd[q * 4 + 1] * w4.y + sd[q * 4 + 2] * w4.z + sd[q * 4 + 3] * w4.w;
    }
    dt[(size_t)l * DINNER + e] = (a > 20.f) ? a : log1pf(__expf(a));
}

// fallback-only scan (reads precomputed dt)
template <typename OT>
__global__ __launch_bounds__(64) void scan_kernel(
    const float* __restrict__ dt, const float* __restrict__ dbl,
    const float* __restrict__ xc, const float* __restrict__ xz,
    const float* __restrict__ alog, const float* __restrict__ dpar,
    OT* __restrict__ yf)
{
    int d0 = blockIdx.x * 4;
    int lane = threadIdx.x;
    int n = lane & 15;
    int dloc = lane >> 4;
    int d = d0 + dloc;
    float A = -__expf(alog[d * 16 + n]);
    float Dq[4];
#pragma unroll
    for (int q = 0; q < 4; ++q) Dq[q] = dpar[d0 + q];

    __shared__ float sdt[64][4];
    __shared__ float sxc[64][4];
    __shared__ float sz[64][4];
    __shared__ float sB[64][16];
    __shared__ float sC[64][16];
    __shared__ float pp[4][64][17];

    float s = 0.f;
    for (int c0 = 0; c0 < SEQL; c0 += 64) {
        int l = c0 + lane;
        *(float4*)&sdt[lane][0] = *(const float4*)&dt[(size_t)l * DINNER + d0];
        *(float4*)&sxc[lane][0] = *(const float4*)&xc[(size_t)l * DINNER + d0];
        *(float4*)&sz[lane][0]  = *(const float4*)&xz[(size_t)l * 3072 + DINNER + d0];
#pragma unroll
        for (int q = 0; q < 4; ++q) {
            *(float4*)&sB[lane][q * 4] = *(const float4*)&dbl[l * 80 + 48 + q * 4];
            *(float4*)&sC[lane][q * 4] = *(const float4*)&dbl[l * 80 + 64 + q * 4];
        }
        __syncthreads();
#pragma unroll 4
        for (int j = 0; j < 64; ++j) {
            float dtv = sdt[j][dloc];
            float xv  = sxc[j][dloc];
            float a = __expf(dtv * A);
            s = fmaf(a, s, dtv * sB[j][n] * xv);
            pp[dloc][j][n] = s * sC[j][n];
        }
        __syncthreads();
#pragma unroll
        for (int q = 0; q < 4; ++q) {
            float accv = 0.f;
#pragma unroll
            for (int nn = 0; nn < 16; ++nn) accv += pp[q][lane][nn];
            float xv = sxc[lane][q];
            float zv = sz[lane][q];
            float sig = 1.f / (1.f + __expf(-zv));
            float v = (accv + xv * Dq[q]) * (zv * sig);
            if constexpr (sizeof(OT) == 2) yf[(size_t)(c0 + lane) * DINNER + d0 + q] = f2bf(v);
            else                           yf[(size_t)(c0 + lane) * DINNER + d0 + q] = v;
        }
        __syncthreads();
    }
}

// ---------------------------------------------------------------------------
// main-path scan: dtproj fused (R6) + T14 async-stage (R7): next chunk's
// global loads issued into REGISTERS before the serial inner loop, LDS-write
// after the barrier -- hides the per-chunk HBM/L2 latency (16 exposed
// round-trips/block before) under the compute phase.
// ---------------------------------------------------------------------------
__global__ __launch_bounds__(64) void scan_fused_kernel(
    const float* __restrict__ dbl, const float* __restrict__ xc,
    const float* __restrict__ xz, const float* __restrict__ dtw,
    const float* __restrict__ dtb, const float* __restrict__ alog,
    const float* __restrict__ dpar, unsigned short* __restrict__ yf)
{
    int d0 = blockIdx.x * 4;
    int lane = threadIdx.x;
    int n = lane & 15;
    int dloc = lane >> 4;
    int d = d0 + dloc;
    float A = -__expf(alog[d * 16 + n]);
    float Dq[4], dtbq[4];
#pragma unroll
    for (int q = 0; q < 4; ++q) { Dq[q] = dpar[d0 + q]; dtbq[q] = dtb[d0 + q]; }

    __shared__ float swt[4][48];     // dtw rows for the 4 channels
    for (int t = lane; t < 192; t += 64)
        swt[t / 48][t % 48] = dtw[(size_t)(d0 + t / 48) * 48 + t % 48];

    __shared__ float sdt[64][4];
    __shared__ float sxc[64][4];
    __shared__ float sz[64][4];
    __shared__ float sB[64][16];
    __shared__ float sC[64][16];
    __shared__ float pp[4][64][17];

    // chunk registers (prefetched)
    float4 rxc, rz, rdb[12], rB[4], rC[4];

    auto loadchunk = [&](int c0) {
        int l = c0 + lane;
        rxc = *(const float4*)&xc[(size_t)l * DINNER + d0];
        rz  = *(const float4*)&xz[(size_t)l * 3072 + DINNER + d0];
#pragma unroll
        for (int q4 = 0; q4 < 12; ++q4)
            rdb[q4] = *(const float4*)&dbl[l * 80 + q4 * 4];
#pragma unroll
        for (int q = 0; q < 4; ++q) {
            rB[q] = *(const float4*)&dbl[l * 80 + 48 + q * 4];
            rC[q] = *(const float4*)&dbl[l * 80 + 64 + q * 4];
        }
    };

    loadchunk(0);
    __syncthreads();                 // swt ready

    float s = 0.f;
    for (int c0 = 0; c0 < SEQL; c0 += 64) {
        // LDS writes from regs + fused dtproj
        *(float4*)&sxc[lane][0] = rxc;
        *(float4*)&sz[lane][0]  = rz;
#pragma unroll
        for (int q = 0; q < 4; ++q) {
            *(float4*)&sB[lane][q * 4] = rB[q];
            *(float4*)&sC[lane][q * 4] = rC[q];
        }
#pragma unroll
        for (int q = 0; q < 4; ++q) {
            float a = dtbq[q];
#pragma unroll
            for (int q4 = 0; q4 < 12; ++q4) {
                float4 w4 = *(const float4*)&swt[q][q4 * 4];
                a += rdb[q4].x * w4.x + rdb[q4].y * w4.y + rdb[q4].z * w4.z + rdb[q4].w * w4.w;
            }
            sdt[lane][q] = (a > 20.f) ? a : log1pf(__expf(a));
        }
        // keep own-lane values for the epilogue (regs survive prefetch)
        float excv[4] = { rxc.x, rxc.y, rxc.z, rxc.w };
        float ezv[4]  = { rz.x,  rz.y,  rz.z,  rz.w  };
        __syncthreads();

        if (c0 + 64 < SEQL) loadchunk(c0 + 64);   // async: hides under compute

#pragma unroll 4
        for (int j = 0; j < 64; ++j) {
            float dtv = sdt[j][dloc];
            float xv  = sxc[j][dloc];
            float a = __expf(dtv * A);
            s = fmaf(a, s, dtv * sB[j][n] * xv);
            pp[dloc][j][n] = s * sC[j][n];
        }
        __syncthreads();
#pragma unroll
        for (int q = 0; q < 4; ++q) {
            float accv = 0.f;
#pragma unroll
            for (int nn = 0; nn < 16; ++nn) accv += pp[q][lane][nn];
            float zv = ezv[q];
            float sig = 1.f / (1.f + __expf(-zv));
            float v = (accv + excv[q] * Dq[q]) * (zv * sig);
            yf[(size_t)(c0 + lane) * DINNER + d0 + q] = f2bf(v);
        }
        __syncthreads();
    }
}

// ---------------------------------------------------------------------------
extern "C" void kernel_launch(void* const* d_in, const int* in_sizes, int n_in,
                              void* d_out, int out_size, void* d_ws, size_t ws_size,
                              hipStream_t stream)
{
    const int*   ids  = (const int*)d_in[0];
    const float* emb  = (const float*)d_in[1];
    const float* inw  = (const float*)d_in[2];
    const float* cw   = (const float*)d_in[3];
    const float* cb   = (const float*)d_in[4];
    const float* xw   = (const float*)d_in[5];
    const float* dtw  = (const float*)d_in[6];
    const float* dtb  = (const float*)d_in[7];
    const float* alog = (const float*)d_in[8];
    const float* dpar = (const float*)d_in[9];
    const float* ow   = (const float*)d_in[10];
    const float* nw   = (const float*)d_in[11];
    const float* nfw  = (const float*)d_in[12];
    float* out = (float*)d_out;

    const size_t MAIN_WS = 138936320ull;

    if (ws_size >= MAIN_WS) {
        char* p = (char*)d_ws;
        float* h    = (float*)p;                 p += (size_t)SEQL * DMODEL * 4;
        float* xz   = (float*)p;                 p += (size_t)SEQL * 3072 * 4;
        float* xc   = (float*)p;                 p += (size_t)SEQL * DINNER * 4;
        float* dbl  = (float*)p;                 p += (size_t)SEQL * 80 * 4;
        float* dt_unused = (float*)p;            p += (size_t)SEQL * DINNER * 4;
        unsigned short* xnB  = (unsigned short*)p; p += (size_t)SEQL * DMODEL * 2;
        unsigned short* yfB  = (unsigned short*)p; p += (size_t)SEQL * DINNER * 2;
        unsigned short* embB = (unsigned short*)p; p += (size_t)VOCABPAD * DMODEL * 2;
        unsigned short* inwB = (unsigned short*)p; p += (size_t)N_LAYER * 3072 * DMODEL * 2;
        unsigned short* owB  = (unsigned short*)p; p += (size_t)N_LAYER * DMODEL * DINNER * 2;
        (void)dt_unused;

        // scratch in the (write-only-at-end) logits output buffer:
        // xwB 1.5MB | xcB 3MB | hp 12.6MB | xpp 2.6MB. All consumed before
        // gemm_logits writes out. No MAIN_WS growth.
        unsigned short* xwB = (unsigned short*)out;
        unsigned short* xcB = xwB + (size_t)N_LAYER * 128 * DINNER;
        float* hp  = (float*)(xcB + (size_t)SEQL * DINNER);
        float* xpp = hp + (size_t)4 * HPSTRIDE;

        const int n0 = VOCABSZ * DMODEL / 8;
        const int n1 = N_LAYER * 3072 * DMODEL / 8;
        const int n2 = N_LAYER * DMODEL * DINNER / 8;
        cvt3_kernel<<<(n0 + n1 + n2 + 255) / 256, 256, 0, stream>>>(
            emb, embB, n0, inw, inwB, n1, ow, owB, n2);
        cvt_xw_kernel<<<(N_LAYER * 128 * 192 + 255) / 256, 256, 0, stream>>>(xw, xwB);

        embed_kernel<<<SEQL, 256, 0, stream>>>(ids, emb, h);

        for (int i = 0; i < N_LAYER; ++i) {
            if (i == 0)
                rmsnorm_kernel<unsigned short><<<SEQL, 256, 0, stream>>>(
                    h, nw, xnB, DMODEL);
            else
                rmsnorm_acc_kernel<<<SEQL, 256, 0, stream>>>(
                    h, hp, nw + (size_t)i * DMODEL, xnB);
            gemm_in_kernel<<<8 * (3072 / 128), 256, 0, stream>>>(
                xnB, inwB + (size_t)i * 3072 * DMODEL, xz, 3072, DMODEL);
            conv_silu_kernel<<<SEQL * 6, 256, 0, stream>>>(
                xz, cw + (size_t)i * DINNER * 4, cb + (size_t)i * DINNER, xc, xcB);
            gemm_xprojk_kernel<<<64, 256, 0, stream>>>(
                xcB, xwB + (size_t)i * 128 * DINNER, xpp);
            xred_kernel<<<(XPSTRIDE / 4 + 255) / 256, 256, 0, stream>>>(xpp, dbl);
            scan_fused_kernel<<<DINNER / 4, 64, 0, stream>>>(
                dbl, xc, xz, dtw + (size_t)i * DINNER * DTRANK,
                dtb + (size_t)i * DINNER, alog + (size_t)i * DINNER * DSTATE,
                dpar + (size_t)i * DINNER, yfB);
            gemm_outp_kernel<<<4 * 48, 256, 0, stream>>>(
                yfB, owB + (size_t)i * DMODEL * DINNER, hp, DMODEL, DINNER, DINNER / 4);
        }

        rmsnorm_acc_kernel<<<SEQL, 256, 0, stream>>>(h, hp, nfw, xnB);
        gemm_logits_kernel<<<8 * ((VOCABSZ + 127) / 128), 256, 0, stream>>>(
            xnB, embB, out, VOCABSZ, DMODEL);
    } else {
        // fallback: R0 fp32 path (ws >= 38 MB verified)
        float* h   = (float*)d_ws;
        float* xn  = h  + (size_t)SEQL * DMODEL;
        float* xz  = xn + (size_t)SEQL * DMODEL;
        float* xc  = xz + (size_t)SEQL * 3072;
        float* dbl = xc + (size_t)SEQL * DINNER;
        float* dt  = dbl + (size_t)SEQL * 80;
        float* yf  = dt + (size_t)SEQL * DINNER;
        unsigned short* xcB = (unsigned short*)out;   // scratch, overwritten at end

        embed_kernel<<<SEQL, 256, 0, stream>>>(ids, emb, h);
        for (int i = 0; i < N_LAYER; ++i) {
            rmsnorm_kernel<float><<<SEQL, 256, 0, stream>>>(h, nw + (size_t)i * DMODEL, xn, DMODEL);
            gemm_fb_kernel<0><<<dim3(3072 / 128, SEQL / 128), 256, 0, stream>>>(
                xn, inw + (size_t)i * 3072 * DMODEL, nullptr, xz, 3072, DMODEL);
            conv_silu_kernel<<<SEQL * 6, 256, 0, stream>>>(
                xz, cw + (size_t)i * DINNER * 4, cb + (size_t)i * DINNER, xc, xcB);
            xproj_kernel<<<SEQL, 256, 0, stream>>>(xc, xw + (size_t)i * 80 * DINNER, dbl);
            dtproj_kernel<<<SEQL * 6, 256, 0, stream>>>(
                dbl, dtw + (size_t)i * DINNER * DTRANK, dtb + (size_t)i * DINNER, dt);
            scan_kernel<float><<<DINNER / 4, 64, 0, stream>>>(
                dt, dbl, xc, xz, alog + (size_t)i * DINNER * DSTATE, dpar + (size_t)i * DINNER, yf);
            gemm_fb_kernel<1><<<dim3(DMODEL / 128, SEQL / 128), 256, 0, stream>>>(
                yf, ow + (size_t)i * DMODEL * DINNER, h, h, DMODEL, DINNER);
        }
        rmsnorm_kernel<float><<<SEQL, 256, 0, stream>>>(h, nfw, xn, DMODEL);
        gemm_fb_kernel<0><<<dim3((VOCABSZ + 127) / 128, SEQL / 128), 256, 0, stream>>>(
            xn, emb, nullptr, out, VOCABSZ, DMODEL);
    }
}

// Round 8
// 1056.130 us; speedup vs baseline: 1.2227x; 1.0466x over previous
//
#include <hip/hip_runtime.h>
#include <cstdint>
#include <cstddef>

#define N_LAYER 4
#define VOCABSZ 50280
#define VOCABPAD 50304
#define DMODEL 768
#define DINNER 1536
#define DSTATE 16
#define DTRANK 48
#define SEQL 1024
#define HPSTRIDE (SEQL * DMODEL)
#define XPSTRIDE (SEQL * 80)
#define NSEG 16
#define DN (DINNER * DSTATE)

typedef __bf16 bf16x8 __attribute__((ext_vector_type(8)));
typedef unsigned short us8 __attribute__((ext_vector_type(8)));
typedef float f32x4 __attribute__((ext_vector_type(4)));

__device__ __forceinline__ unsigned short f2bf(float f) {
    unsigned int u = __builtin_bit_cast(unsigned int, f);
    u = (u + 0x7FFFu + ((u >> 16) & 1u)) >> 16;   // round-to-nearest-even
    return (unsigned short)u;
}

__device__ __forceinline__ void glds16(const unsigned short* g, unsigned short* l) {
    __builtin_amdgcn_global_load_lds(
        (const __attribute__((address_space(1))) void*)g,
        (__attribute__((address_space(3))) void*)l, 16, 0, 0);
}

__device__ __forceinline__ void cvt8(const float* s, unsigned short* d) {
    const float4* s4 = (const float4*)s;
    float4 a = s4[0], b = s4[1];
    us8 o = { f2bf(a.x), f2bf(a.y), f2bf(a.z), f2bf(a.w),
              f2bf(b.x), f2bf(b.y), f2bf(b.z), f2bf(b.w) };
    *(us8*)d = o;
}

// ---------------------------------------------------------------------------
// fp32 -> bf16 bulk convert (8 elems/thread)
// ---------------------------------------------------------------------------
__global__ __launch_bounds__(256) void cvt_bf16_kernel(
    const float* __restrict__ src, unsigned short* __restrict__ dst, int n8)
{
    int i = blockIdx.x * 256 + threadIdx.x;
    if (i >= n8) return;
    cvt8(src + (size_t)i * 8, dst + (size_t)i * 8);
}

// three fp32->bf16 conversions in ONE launch (emb, in_proj_w, out_proj_w)
__global__ __launch_bounds__(256) void cvt3_kernel(
    const float* __restrict__ s0, unsigned short* __restrict__ d0, int n0,
    const float* __restrict__ s1, unsigned short* __restrict__ d1, int n1,
    const float* __restrict__ s2, unsigned short* __restrict__ d2, int n2)
{
    int i = blockIdx.x * 256 + threadIdx.x;
    const float* s; unsigned short* d; int j = i;
    if (j < n0) { s = s0; d = d0; }
    else {
        j -= n0;
        if (j < n1) { s = s1; d = d1; }
        else {
            j -= n1;
            if (j >= n2) return;
            s = s2; d = d2;
        }
    }
    cvt8(s + (size_t)j * 8, d + (size_t)j * 8);
}

// ---------------------------------------------------------------------------
// x_proj_w (N_LAYER,80,1536) fp32 -> bf16, padded to 128 rows/layer
// ---------------------------------------------------------------------------
__global__ __launch_bounds__(256) void cvt_xw_kernel(
    const float* __restrict__ xw, unsigned short* __restrict__ xwB)
{
    int g = blockIdx.x * 256 + threadIdx.x;
    if (g >= N_LAYER * 128 * 192) return;
    int row = g / 192;
    int c8  = g % 192;
    int layer = row >> 7;
    int r = row & 127;
    us8 o;
    if (r < 80) {
        const float4* s = (const float4*)(xw + ((size_t)(layer * 80 + r) * DINNER) + c8 * 8);
        float4 a = s[0], b = s[1];
        o = (us8){ f2bf(a.x), f2bf(a.y), f2bf(a.z), f2bf(a.w),
                   f2bf(b.x), f2bf(b.y), f2bf(b.z), f2bf(b.w) };
    } else {
        o = (us8){0, 0, 0, 0, 0, 0, 0, 0};
    }
    *(us8*)(xwB + (size_t)row * DINNER + c8 * 8) = o;
}

// ---------------------------------------------------------------------------
// shared MFMA compute for 128x128 tile fragments
// ---------------------------------------------------------------------------
__device__ __forceinline__ void gemm_compute32(
    const unsigned short* sAbuf, const unsigned short* sBbuf,
    int wm, int wn, int frs, f32x4 (&acc)[4][4])
{
    bf16x8 af[4], bfr[4];
#pragma unroll
    for (int t = 0; t < 4; ++t) {
        af[t]  = __builtin_bit_cast(bf16x8, *(const us8*)&sAbuf[(wm + t * 16) * 32 + frs]);
        bfr[t] = __builtin_bit_cast(bf16x8, *(const us8*)&sBbuf[(wn + t * 16) * 32 + frs]);
    }
#pragma unroll
    for (int mt = 0; mt < 4; ++mt)
#pragma unroll
        for (int nt = 0; nt < 4; ++nt)
            acc[mt][nt] = __builtin_amdgcn_mfma_f32_16x16x32_bf16(
                af[mt], bfr[nt], acc[mt][nt], 0, 0, 0);
}

// ---------------------------------------------------------------------------
// 2-phase double-buffered core (R5): per-layer GEMMs (-80us aggregate there).
// ---------------------------------------------------------------------------
__device__ __forceinline__ void gemm_core(
    const unsigned short* __restrict__ A, const unsigned short* __restrict__ B,
    float* __restrict__ C, int N, int Kstride, int Klen, int bm, int bn)
{
    __shared__ unsigned short sA0[128 * 32];
    __shared__ unsigned short sA1[128 * 32];
    __shared__ unsigned short sB0[128 * 32];
    __shared__ unsigned short sB1[128 * 32];

    const int tid  = threadIdx.x;
    const int lane = tid & 63;
    const int wave = tid >> 6;
    const int wm = (wave & 1) * 64;
    const int wn = (wave >> 1) * 64;

    const int scol = ((tid & 3) ^ ((tid >> 3) & 3)) * 8;
    const unsigned short* Ag0 = A + (size_t)(bm + (tid >> 2)) * Kstride + scol;
    const unsigned short* Ag1 = Ag0 + (size_t)64 * Kstride;
    const unsigned short* Bg0 = B + (size_t)(bn + (tid >> 2)) * Kstride + scol;
    const unsigned short* Bg1 = Bg0 + (size_t)64 * Kstride;
    unsigned short* lA0a = sA0 + tid * 8;  unsigned short* lA0b = lA0a + 2048;
    unsigned short* lA1a = sA1 + tid * 8;  unsigned short* lA1b = lA1a + 2048;
    unsigned short* lB0a = sB0 + tid * 8;  unsigned short* lB0b = lB0a + 2048;
    unsigned short* lB1a = sB1 + tid * 8;  unsigned short* lB1b = lB1a + 2048;

    f32x4 acc[4][4];
#pragma unroll
    for (int i = 0; i < 4; ++i)
#pragma unroll
        for (int j = 0; j < 4; ++j) acc[i][j] = (f32x4){0.f, 0.f, 0.f, 0.f};

    const int frs = (lane & 15) * 32 + (((lane >> 4) ^ ((lane >> 1) & 3))) * 8;

    glds16(Ag0, lA0a); glds16(Ag1, lA0b);
    glds16(Bg0, lB0a); glds16(Bg1, lB0b);
    Ag0 += 32; Ag1 += 32; Bg0 += 32; Bg1 += 32;
    __syncthreads();

    for (int k0 = 0; k0 < Klen; k0 += 64) {
        glds16(Ag0, lA1a); glds16(Ag1, lA1b);
        glds16(Bg0, lB1a); glds16(Bg1, lB1b);
        Ag0 += 32; Ag1 += 32; Bg0 += 32; Bg1 += 32;
        gemm_compute32(sA0, sB0, wm, wn, frs, acc);
        __syncthreads();

        if (k0 + 64 < Klen) {
            glds16(Ag0, lA0a); glds16(Ag1, lA0b);
            glds16(Bg0, lB0a); glds16(Bg1, lB0b);
            Ag0 += 32; Ag1 += 32; Bg0 += 32; Bg1 += 32;
        }
        gemm_compute32(sA1, sB1, wm, wn, frs, acc);
        __syncthreads();
    }

    const int cn = lane & 15;
    const int cm = (lane >> 4) * 4;
#pragma unroll
    for (int mt = 0; mt < 4; ++mt) {
#pragma unroll
        for (int nt = 0; nt < 4; ++nt) {
            int n = bn + wn + nt * 16 + cn;
            if (n < N) {
#pragma unroll
                for (int r = 0; r < 4; ++r) {
                    int m = bm + wm + mt * 16 + cm + r;
                    C[(size_t)m * N + n] = acc[mt][nt][r];
                }
            }
        }
    }
}

// XCD-swizzled mapping (grid%8==0)
__device__ __forceinline__ void swz_mn(int bid, int grid, int& bm, int& bn)
{
    int cpx = grid >> 3;
    int swz = (bid & 7) * cpx + (bid >> 3);
    bm = (swz & 7) << 7;
    bn = (swz >> 3) << 7;
}

__global__ __launch_bounds__(256) void gemm_in_kernel(
    const unsigned short* __restrict__ A, const unsigned short* __restrict__ B,
    float* __restrict__ C, int N, int K)
{ int bm, bn; swz_mn(blockIdx.x, gridDim.x, bm, bn); gemm_core(A, B, C, N, K, K, bm, bn); }

// split-K x8 xproj (R7): grid 64; partials -> xpp; reduced by xred_kernel.
__global__ __launch_bounds__(256) void gemm_xprojk_kernel(
    const unsigned short* __restrict__ A, const unsigned short* __restrict__ B,
    float* __restrict__ xpp)
{
    int split = blockIdx.x >> 3;
    int bm = (blockIdx.x & 7) << 7;
    int kbase = split * 192;
    gemm_core(A + kbase, B + kbase, xpp + (size_t)split * XPSTRIDE,
              80, DINNER, 192, bm, 0);
}

__global__ __launch_bounds__(256) void xred_kernel(
    const float* __restrict__ xpp, float* __restrict__ dbl)
{
    int i = blockIdx.x * 256 + threadIdx.x;     // float4 index
    if (i >= XPSTRIDE / 4) return;
    const f32x4* p = (const f32x4*)xpp + i;
    f32x4 s = p[0];
#pragma unroll
    for (int k = 1; k < 8; ++k) s += p[(size_t)k * (XPSTRIDE / 4)];
    ((f32x4*)dbl)[i] = s;
}

// split-K x4 gemm_out (R6): partials into hp[split]; reduced by rmsnorm_acc.
__global__ __launch_bounds__(256) void gemm_outp_kernel(
    const unsigned short* __restrict__ A, const unsigned short* __restrict__ B,
    float* __restrict__ hp, int N, int Kstride, int Klen)
{
    int bid = blockIdx.x;
    int split = bid / 48;
    int r = bid - split * 48;
    int swz = (r & 7) * 6 + (r >> 3);        // bijective over 0..47
    int bm = (swz & 7) << 7;
    int bn = (swz >> 3) << 7;
    int kbase = split * Klen;
    gemm_core(A + kbase, B + kbase, hp + (size_t)split * HPSTRIDE,
              N, Kstride, Klen, bm, bn);
}

// ---------------------------------------------------------------------------
// logits GEMM: 1-phase 16KB body (R4/R7-best: 152us @ occ 34%).
// ---------------------------------------------------------------------------
__global__ __launch_bounds__(256) void gemm_logits_kernel(
    const unsigned short* __restrict__ A, const unsigned short* __restrict__ B,
    float* __restrict__ C, int N, int K)
{
    __shared__ unsigned short sA[128 * 32];
    __shared__ unsigned short sB[128 * 32];

    const int tid  = threadIdx.x;
    const int lane = tid & 63;
    const int wave = tid >> 6;
    const int wm = (wave & 1) * 64;
    const int wn = (wave >> 1) * 64;
    int bm, bn;
    swz_mn(blockIdx.x, gridDim.x, bm, bn);

    const int scol = ((tid & 3) ^ ((tid >> 3) & 3)) * 8;
    const unsigned short* Ag0 = A + (size_t)(bm + (tid >> 2)) * K + scol;
    const unsigned short* Ag1 = Ag0 + (size_t)64 * K;
    const unsigned short* Bg0 = B + (size_t)(bn + (tid >> 2)) * K + scol;
    const unsigned short* Bg1 = Bg0 + (size_t)64 * K;
    unsigned short* lA0 = sA + tid * 8;
    unsigned short* lA1 = lA0 + 2048;
    unsigned short* lB0 = sB + tid * 8;
    unsigned short* lB1 = lB0 + 2048;

    f32x4 acc[4][4];
#pragma unroll
    for (int i = 0; i < 4; ++i)
#pragma unroll
        for (int j = 0; j < 4; ++j) acc[i][j] = (f32x4){0.f, 0.f, 0.f, 0.f};

    const int frs = (lane & 15) * 32 + (((lane >> 4) ^ ((lane >> 1) & 3))) * 8;

    for (int k0 = 0; k0 < K; k0 += 32) {
        __syncthreads();
        glds16(Ag0, lA0);
        glds16(Ag1, lA1);
        glds16(Bg0, lB0);
        glds16(Bg1, lB1);
        Ag0 += 32; Ag1 += 32; Bg0 += 32; Bg1 += 32;
        __syncthreads();
        gemm_compute32(sA, sB, wm, wn, frs, acc);
    }

    const int cn = lane & 15;
    const int cm = (lane >> 4) * 4;
#pragma unroll
    for (int mt = 0; mt < 4; ++mt) {
#pragma unroll
        for (int nt = 0; nt < 4; ++nt) {
            int n = bn + wn + nt * 16 + cn;
            if (n < N) {
#pragma unroll
                for (int r = 0; r < 4; ++r) {
                    int m = bm + wm + mt * 16 + cm + r;
                    C[(size_t)m * N + n] = acc[mt][nt][r];
                }
            }
        }
    }
}

// ---------------------------------------------------------------------------
// fallback fp32 GEMM (R0 code, known-pass) for small-ws safety
// ---------------------------------------------------------------------------
template <int ADD>
__global__ __launch_bounds__(256) void gemm_fb_kernel(
    const float* __restrict__ A, const float* __restrict__ B,
    const float* __restrict__ ADDSRC, float* __restrict__ C,
    int N, int K)
{
    __shared__ unsigned short sA[128 * 40];
    __shared__ unsigned short sB[128 * 40];
    const int tid  = threadIdx.x;
    const int lane = tid & 63;
    const int wave = tid >> 6;
    const int wm = (wave & 1) * 64;
    const int wn = (wave >> 1) * 64;
    const int bm = blockIdx.y * 128;
    const int bn = blockIdx.x * 128;
    const int srow = tid >> 1;
    const int scol = (tid & 1) * 16;
    const float* Ap = A + (size_t)(bm + srow) * K + scol;
    const int brow  = bn + srow;
    const bool bvalid = brow < N;
    const float* Bp = B + (size_t)(bvalid ? brow : 0) * K + scol;
    f32x4 acc[4][4];
#pragma unroll
    for (int i = 0; i < 4; ++i)
#pragma unroll
        for (int j = 0; j < 4; ++j) acc[i][j] = (f32x4){0.f, 0.f, 0.f, 0.f};
    unsigned short* sAp = &sA[srow * 40 + scol];
    unsigned short* sBp = &sB[srow * 40 + scol];
    const int fr = (lane & 15) * 40 + (lane >> 4) * 8;
    for (int k0 = 0; k0 < K; k0 += 32) {
        float4 a0 = *(const float4*)(Ap + k0);
        float4 a1 = *(const float4*)(Ap + k0 + 4);
        float4 a2 = *(const float4*)(Ap + k0 + 8);
        float4 a3 = *(const float4*)(Ap + k0 + 12);
        float4 b0, b1, b2, b3;
        if (bvalid) {
            b0 = *(const float4*)(Bp + k0);
            b1 = *(const float4*)(Bp + k0 + 4);
            b2 = *(const float4*)(Bp + k0 + 8);
            b3 = *(const float4*)(Bp + k0 + 12);
        } else {
            b0 = make_float4(0.f, 0.f, 0.f, 0.f);
            b1 = b0; b2 = b0; b3 = b0;
        }
        __syncthreads();
        us8 va0 = { f2bf(a0.x), f2bf(a0.y), f2bf(a0.z), f2bf(a0.w),
                    f2bf(a1.x), f2bf(a1.y), f2bf(a1.z), f2bf(a1.w) };
        us8 va1 = { f2bf(a2.x), f2bf(a2.y), f2bf(a2.z), f2bf(a2.w),
                    f2bf(a3.x), f2bf(a3.y), f2bf(a3.z), f2bf(a3.w) };
        us8 vb0 = { f2bf(b0.x), f2bf(b0.y), f2bf(b0.z), f2bf(b0.w),
                    f2bf(b1.x), f2bf(b1.y), f2bf(b1.z), f2bf(b1.w) };
        us8 vb1 = { f2bf(b2.x), f2bf(b2.y), f2bf(b2.z), f2bf(b2.w),
                    f2bf(b3.x), f2bf(b3.y), f2bf(b3.z), f2bf(b3.w) };
        *(us8*)(sAp)     = va0;
        *(us8*)(sAp + 8) = va1;
        *(us8*)(sBp)     = vb0;
        *(us8*)(sBp + 8) = vb1;
        __syncthreads();
        bf16x8 af[4], bfr[4];
#pragma unroll
        for (int t = 0; t < 4; ++t) {
            af[t]  = __builtin_bit_cast(bf16x8, *(const us8*)&sA[wm * 40 + t * 640 + fr]);
            bfr[t] = __builtin_bit_cast(bf16x8, *(const us8*)&sB[wn * 40 + t * 640 + fr]);
        }
#pragma unroll
        for (int mt = 0; mt < 4; ++mt)
#pragma unroll
            for (int nt = 0; nt < 4; ++nt)
                acc[mt][nt] = __builtin_amdgcn_mfma_f32_16x16x32_bf16(
                    af[mt], bfr[nt], acc[mt][nt], 0, 0, 0);
    }
    const int cn = lane & 15;
    const int cm = (lane >> 4) * 4;
#pragma unroll
    for (int mt = 0; mt < 4; ++mt) {
#pragma unroll
        for (int nt = 0; nt < 4; ++nt) {
            int n = bn + wn + nt * 16 + cn;
            if (n < N) {
#pragma unroll
                for (int r = 0; r < 4; ++r) {
                    int m = bm + wm + mt * 16 + cm + r;
                    size_t idx = (size_t)m * N + n;
                    float v = acc[mt][nt][r];
                    if constexpr (ADD) v += ADDSRC[idx];
                    C[idx] = v;
                }
            }
        }
    }
}

// ---------------------------------------------------------------------------
__global__ __launch_bounds__(256) void embed_kernel(
    const int* __restrict__ ids, const float* __restrict__ emb, float* __restrict__ h)
{
    int l = blockIdx.x;
    int id = ids[l];
    const float* src = emb + (size_t)id * DMODEL;
    for (int d = threadIdx.x; d < DMODEL; d += 256) h[(size_t)l * DMODEL + d] = src[d];
}

template <typename OT>
__global__ __launch_bounds__(256) void rmsnorm_kernel(
    const float* __restrict__ x, const float* __restrict__ w,
    OT* __restrict__ out, int D)
{
    int l = blockIdx.x;
    const float* xr = x + (size_t)l * D;
    float ss = 0.f;
    for (int d = threadIdx.x; d < D; d += 256) { float v = xr[d]; ss += v * v; }
#pragma unroll
    for (int off = 32; off > 0; off >>= 1) ss += __shfl_down(ss, off, 64);
    __shared__ float red[4];
    __shared__ float invs;
    if ((threadIdx.x & 63) == 0) red[threadIdx.x >> 6] = ss;
    __syncthreads();
    if (threadIdx.x == 0)
        invs = rsqrtf((red[0] + red[1] + red[2] + red[3]) / (float)D + 1e-5f);
    __syncthreads();
    float inv = invs;
    for (int d = threadIdx.x; d < D; d += 256) {
        float v = xr[d] * inv * w[d];
        if constexpr (sizeof(OT) == 2) out[(size_t)l * D + d] = f2bf(v);
        else                           out[(size_t)l * D + d] = v;
    }
}

// accumulate 4 gemm_out K-split partials + residual into h, then rmsnorm -> bf16
__global__ __launch_bounds__(256) void rmsnorm_acc_kernel(
    float* __restrict__ h, const float* __restrict__ hp,
    const float* __restrict__ w, unsigned short* __restrict__ out)
{
    int l = blockIdx.x;
    const size_t base = (size_t)l * DMODEL;
    __shared__ float row[DMODEL];
    float ss = 0.f;
    for (int d = threadIdx.x; d < DMODEL; d += 256) {
        float v = h[base + d]
                + hp[base + d]
                + hp[base + d + (size_t)HPSTRIDE]
                + hp[base + d + (size_t)2 * HPSTRIDE]
                + hp[base + d + (size_t)3 * HPSTRIDE];
        row[d] = v;
        h[base + d] = v;
        ss += v * v;
    }
#pragma unroll
    for (int off = 32; off > 0; off >>= 1) ss += __shfl_down(ss, off, 64);
    __shared__ float red[4];
    __shared__ float invs;
    if ((threadIdx.x & 63) == 0) red[threadIdx.x >> 6] = ss;
    __syncthreads();
    if (threadIdx.x == 0)
        invs = rsqrtf((red[0] + red[1] + red[2] + red[3]) / (float)DMODEL + 1e-5f);
    __syncthreads();
    float inv = invs;
    for (int d = threadIdx.x; d < DMODEL; d += 256)
        out[base + d] = f2bf(row[d] * inv * w[d]);
}

// conv+silu; emits fp32 xc (scan) and bf16 xcB (xproj GEMM A-operand)
__global__ __launch_bounds__(256) void conv_silu_kernel(
    const float* __restrict__ xz, const float* __restrict__ cw,
    const float* __restrict__ cb, float* __restrict__ xc,
    unsigned short* __restrict__ xcB)
{
    int l = blockIdx.x / 6;
    int d = (blockIdx.x % 6) * 256 + threadIdx.x;
    float w0 = cw[d * 4], w1 = cw[d * 4 + 1], w2 = cw[d * 4 + 2], w3 = cw[d * 4 + 3];
    float acc = cb[d];
    if (l >= 3) acc += xz[(size_t)(l - 3) * 3072 + d] * w0;
    if (l >= 2) acc += xz[(size_t)(l - 2) * 3072 + d] * w1;
    if (l >= 1) acc += xz[(size_t)(l - 1) * 3072 + d] * w2;
    acc += xz[(size_t)l * 3072 + d] * w3;
    float sig = 1.f / (1.f + __expf(-acc));
    float v = acc * sig;
    size_t idx = (size_t)l * DINNER + d;
    xc[idx]  = v;
    xcB[idx] = f2bf(v);
}

// fallback-only fp32 xproj
__global__ __launch_bounds__(256) void xproj_kernel(
    const float* __restrict__ xc, const float* __restrict__ xw, float* __restrict__ dbl)
{
    int l = blockIdx.x;
    __shared__ float sx[DINNER];
    for (int d = threadIdx.x; d < DINNER; d += 256) sx[d] = xc[(size_t)l * DINNER + d];
    __syncthreads();
    int wave = threadIdx.x >> 6, lane = threadIdx.x & 63;
    for (int e = wave * 20; e < wave * 20 + 20; ++e) {
        const float* wr = xw + (size_t)e * DINNER;
        float s = 0.f;
        for (int d = lane; d < DINNER; d += 64) s += sx[d] * wr[d];
#pragma unroll
        for (int off = 32; off > 0; off >>= 1) s += __shfl_down(s, off, 64);
        if (lane == 0) dbl[l * 80 + e] = s;
    }
}

// fallback-only dtproj
__global__ __launch_bounds__(256) void dtproj_kernel(
    const float* __restrict__ dbl, const float* __restrict__ dtw,
    const float* __restrict__ dtb, float* __restrict__ dt)
{
    int l = blockIdx.x / 6;
    int e = (blockIdx.x % 6) * 256 + threadIdx.x;
    __shared__ float sd[48];
    if (threadIdx.x < 48) sd[threadIdx.x] = dbl[l * 80 + threadIdx.x];
    __syncthreads();
    float a = dtb[e];
    const float4* wr = (const float4*)(dtw + (size_t)e * 48);
#pragma unroll
    for (int q = 0; q < 12; ++q) {
        float4 w4 = wr[q];
        a += sd[q * 4] * w4.x + sd[q * 4 + 1] * w4.y + sd[q * 4 + 2] * w4.z + sd[q * 4 + 3] * w4.w;
    }
    dt[(size_t)l * DINNER + e] = (a > 20.f) ? a : log1pf(__expf(a));
}

// fallback-only scan (reads precomputed dt)
template <typename OT>
__global__ __launch_bounds__(64) void scan_kernel(
    const float* __restrict__ dt, const float* __restrict__ dbl,
    const float* __restrict__ xc, const float* __restrict__ xz,
    const float* __restrict__ alog, const float* __restrict__ dpar,
    OT* __restrict__ yf)
{
    int d0 = blockIdx.x * 4;
    int lane = threadIdx.x;
    int n = lane & 15;
    int dloc = lane >> 4;
    int d = d0 + dloc;
    float A = -__expf(alog[d * 16 + n]);
    float Dq[4];
#pragma unroll
    for (int q = 0; q < 4; ++q) Dq[q] = dpar[d0 + q];

    __shared__ float sdt[64][4];
    __shared__ float sxc[64][4];
    __shared__ float sz[64][4];
    __shared__ float sB[64][16];
    __shared__ float sC[64][16];
    __shared__ float pp[4][64][17];

    float s = 0.f;
    for (int c0 = 0; c0 < SEQL; c0 += 64) {
        int l = c0 + lane;
        *(float4*)&sdt[lane][0] = *(const float4*)&dt[(size_t)l * DINNER + d0];
        *(float4*)&sxc[lane][0] = *(const float4*)&xc[(size_t)l * DINNER + d0];
        *(float4*)&sz[lane][0]  = *(const float4*)&xz[(size_t)l * 3072 + DINNER + d0];
#pragma unroll
        for (int q = 0; q < 4; ++q) {
            *(float4*)&sB[lane][q * 4] = *(const float4*)&dbl[l * 80 + 48 + q * 4];
            *(float4*)&sC[lane][q * 4] = *(const float4*)&dbl[l * 80 + 64 + q * 4];
        }
        __syncthreads();
#pragma unroll 4
        for (int j = 0; j < 64; ++j) {
            float dtv = sdt[j][dloc];
            float xv  = sxc[j][dloc];
            float a = __expf(dtv * A);
            s = fmaf(a, s, dtv * sB[j][n] * xv);
            pp[dloc][j][n] = s * sC[j][n];
        }
        __syncthreads();
#pragma unroll
        for (int q = 0; q < 4; ++q) {
            float accv = 0.f;
#pragma unroll
            for (int nn = 0; nn < 16; ++nn) accv += pp[q][lane][nn];
            float xv = sxc[lane][q];
            float zv = sz[lane][q];
            float sig = 1.f / (1.f + __expf(-zv));
            float v = (accv + xv * Dq[q]) * (zv * sig);
            if constexpr (sizeof(OT) == 2) yf[(size_t)(c0 + lane) * DINNER + d0 + q] = f2bf(v);
            else                           yf[(size_t)(c0 + lane) * DINNER + d0 + q] = v;
        }
        __syncthreads();
    }
}

// ---------------------------------------------------------------------------
// R8 segmented scan: linear recurrence s[l]=a*s[l-1]+b split into NSEG=16
// segments of 64. Pass A computes per-segment (aprod=PRODUCT a, spart=scan
// from 0); pass B sequentially combines the 16 segment summaries per (d,n)
// chain to get each segment's true entry state; pass C recomputes each
// segment from its entry state and emits y. Parallelism 384 -> 6144 waves
// (the old monolith: 0.19% occupancy, 0.7% VALUBusy, 130-208us/layer).
// ---------------------------------------------------------------------------
__global__ __launch_bounds__(64) void scan_partA_kernel(
    const float* __restrict__ dbl, const float* __restrict__ xc,
    const float* __restrict__ dtw, const float* __restrict__ dtb,
    const float* __restrict__ alog,
    float* __restrict__ spart, float* __restrict__ aprod)
{
    int bid  = blockIdx.x;
    int seg  = bid / (DINNER / 4);       // seg-major: same-seg blocks share dbl rows
    int dblk = bid % (DINNER / 4);
    int d0 = dblk * 4;
    int lane = threadIdx.x;
    int n = lane & 15;
    int dloc = lane >> 4;
    int d = d0 + dloc;
    float A = -__expf(alog[d * 16 + n]);
    float dtbq[4];
#pragma unroll
    for (int q = 0; q < 4; ++q) dtbq[q] = dtb[d0 + q];

    __shared__ float swt[4][48];
    for (int t = lane; t < 192; t += 64)
        swt[t / 48][t % 48] = dtw[(size_t)(d0 + t / 48) * 48 + t % 48];

    __shared__ float sdt[64][4];
    __shared__ float sxc[64][4];
    __shared__ float sB[64][16];

    int l = seg * 64 + lane;
    float4 rxc = *(const float4*)&xc[(size_t)l * DINNER + d0];
    float4 rdb[12];
#pragma unroll
    for (int q4 = 0; q4 < 12; ++q4)
        rdb[q4] = *(const float4*)&dbl[l * 80 + q4 * 4];
    float4 rB[4];
#pragma unroll
    for (int q = 0; q < 4; ++q) rB[q] = *(const float4*)&dbl[l * 80 + 48 + q * 4];

    __syncthreads();                     // swt ready
    *(float4*)&sxc[lane][0] = rxc;
#pragma unroll
    for (int q = 0; q < 4; ++q) *(float4*)&sB[lane][q * 4] = rB[q];
#pragma unroll
    for (int q = 0; q < 4; ++q) {
        float a = dtbq[q];
#pragma unroll
        for (int q4 = 0; q4 < 12; ++q4) {
            float4 w4 = *(const float4*)&swt[q][q4 * 4];
            a += rdb[q4].x * w4.x + rdb[q4].y * w4.y + rdb[q4].z * w4.z + rdb[q4].w * w4.w;
        }
        sdt[lane][q] = (a > 20.f) ? a : log1pf(__expf(a));
    }
    __syncthreads();                     // tile ready

    float s = 0.f, ap = 1.f;
#pragma unroll 4
    for (int j = 0; j < 64; ++j) {
        float dtv = sdt[j][dloc];
        float xv  = sxc[j][dloc];
        float a = __expf(dtv * A);
        s = fmaf(a, s, dtv * sB[j][n] * xv);
        ap *= a;
    }
    size_t o = (size_t)seg * DN + (size_t)d * 16 + n;
    spart[o] = s;
    aprod[o] = ap;
}

__global__ __launch_bounds__(256) void scan_fixB_kernel(
    const float* __restrict__ spart, const float* __restrict__ aprod,
    float* __restrict__ sinit)
{
    int i = blockIdx.x * 256 + threadIdx.x;   // (d*16+n), 24576 chains
    if (i >= DN) return;
    float s = 0.f;
#pragma unroll
    for (int k = 0; k < NSEG; ++k) {
        sinit[(size_t)k * DN + i] = s;
        s = aprod[(size_t)k * DN + i] * s + spart[(size_t)k * DN + i];
    }
}

__global__ __launch_bounds__(64) void scan_outC_kernel(
    const float* __restrict__ dbl, const float* __restrict__ xc,
    const float* __restrict__ xz, const float* __restrict__ dtw,
    const float* __restrict__ dtb, const float* __restrict__ alog,
    const float* __restrict__ dpar, const float* __restrict__ sinit,
    unsigned short* __restrict__ yf)
{
    int bid  = blockIdx.x;
    int seg  = bid / (DINNER / 4);
    int dblk = bid % (DINNER / 4);
    int d0 = dblk * 4;
    int lane = threadIdx.x;
    int n = lane & 15;
    int dloc = lane >> 4;
    int d = d0 + dloc;
    float A = -__expf(alog[d * 16 + n]);
    float Dq[4], dtbq[4];
#pragma unroll
    for (int q = 0; q < 4; ++q) { Dq[q] = dpar[d0 + q]; dtbq[q] = dtb[d0 + q]; }

    __shared__ float swt[4][48];
    for (int t = lane; t < 192; t += 64)
        swt[t / 48][t % 48] = dtw[(size_t)(d0 + t / 48) * 48 + t % 48];

    __shared__ float sdt[64][4];
    __shared__ float sxc[64][4];
    __shared__ float sz[64][4];
    __shared__ float sB[64][16];
    __shared__ float sC[64][16];
    __shared__ float pp[4][64][17];

    int l = seg * 64 + lane;
    float4 rxc = *(const float4*)&xc[(size_t)l * DINNER + d0];
    float4 rz  = *(const float4*)&xz[(size_t)l * 3072 + DINNER + d0];
    float4 rdb[12];
#pragma unroll
    for (int q4 = 0; q4 < 12; ++q4)
        rdb[q4] = *(const float4*)&dbl[l * 80 + q4 * 4];
    float4 rB[4], rC[4];
#pragma unroll
    for (int q = 0; q < 4; ++q) {
        rB[q] = *(const float4*)&dbl[l * 80 + 48 + q * 4];
        rC[q] = *(const float4*)&dbl[l * 80 + 64 + q * 4];
    }
    float s = sinit[(size_t)seg * DN + (size_t)d * 16 + n];

    __syncthreads();                     // swt ready
    *(float4*)&sxc[lane][0] = rxc;
    *(float4*)&sz[lane][0]  = rz;
#pragma unroll
    for (int q = 0; q < 4; ++q) {
        *(float4*)&sB[lane][q * 4] = rB[q];
        *(float4*)&sC[lane][q * 4] = rC[q];
    }
#pragma unroll
    for (int q = 0; q < 4; ++q) {
        float a = dtbq[q];
#pragma unroll
        for (int q4 = 0; q4 < 12; ++q4) {
            float4 w4 = *(const float4*)&swt[q][q4 * 4];
            a += rdb[q4].x * w4.x + rdb[q4].y * w4.y + rdb[q4].z * w4.z + rdb[q4].w * w4.w;
        }
        sdt[lane][q] = (a > 20.f) ? a : log1pf(__expf(a));
    }
    float excv[4] = { rxc.x, rxc.y, rxc.z, rxc.w };
    float ezv[4]  = { rz.x,  rz.y,  rz.z,  rz.w  };
    __syncthreads();                     // tile ready

#pragma unroll 4
    for (int j = 0; j < 64; ++j) {
        float dtv = sdt[j][dloc];
        float xv  = sxc[j][dloc];
        float a = __expf(dtv * A);
        s = fmaf(a, s, dtv * sB[j][n] * xv);
        pp[dloc][j][n] = s * sC[j][n];
    }
    __syncthreads();
#pragma unroll
    for (int q = 0; q < 4; ++q) {
        float accv = 0.f;
#pragma unroll
        for (int nn = 0; nn < 16; ++nn) accv += pp[q][lane][nn];
        float zv = ezv[q];
        float sig = 1.f / (1.f + __expf(-zv));
        float v = (accv + excv[q] * Dq[q]) * (zv * sig);
        yf[(size_t)(seg * 64 + lane) * DINNER + d0 + q] = f2bf(v);
    }
}

// ---------------------------------------------------------------------------
extern "C" void kernel_launch(void* const* d_in, const int* in_sizes, int n_in,
                              void* d_out, int out_size, void* d_ws, size_t ws_size,
                              hipStream_t stream)
{
    const int*   ids  = (const int*)d_in[0];
    const float* emb  = (const float*)d_in[1];
    const float* inw  = (const float*)d_in[2];
    const float* cw   = (const float*)d_in[3];
    const float* cb   = (const float*)d_in[4];
    const float* xw   = (const float*)d_in[5];
    const float* dtw  = (const float*)d_in[6];
    const float* dtb  = (const float*)d_in[7];
    const float* alog = (const float*)d_in[8];
    const float* dpar = (const float*)d_in[9];
    const float* ow   = (const float*)d_in[10];
    const float* nw   = (const float*)d_in[11];
    const float* nfw  = (const float*)d_in[12];
    float* out = (float*)d_out;

    const size_t MAIN_WS = 138936320ull;

    if (ws_size >= MAIN_WS) {
        char* p = (char*)d_ws;
        float* h    = (float*)p;                 p += (size_t)SEQL * DMODEL * 4;
        float* xz   = (float*)p;                 p += (size_t)SEQL * 3072 * 4;
        float* xc   = (float*)p;                 p += (size_t)SEQL * DINNER * 4;
        float* dbl  = (float*)p;                 p += (size_t)SEQL * 80 * 4;
        float* dt_unused = (float*)p;            p += (size_t)SEQL * DINNER * 4;
        unsigned short* xnB  = (unsigned short*)p; p += (size_t)SEQL * DMODEL * 2;
        unsigned short* yfB  = (unsigned short*)p; p += (size_t)SEQL * DINNER * 2;
        unsigned short* embB = (unsigned short*)p; p += (size_t)VOCABPAD * DMODEL * 2;
        unsigned short* inwB = (unsigned short*)p; p += (size_t)N_LAYER * 3072 * DMODEL * 2;
        unsigned short* owB  = (unsigned short*)p; p += (size_t)N_LAYER * DMODEL * DINNER * 2;
        (void)dt_unused;

        // scratch in the (write-only-at-end) logits output buffer:
        // xwB 1.5MB | xcB 3MB | hp 12.6MB | xpp 2.6MB | spart/aprod/sinit
        // 3x1.57MB. All consumed before gemm_logits writes out.
        unsigned short* xwB = (unsigned short*)out;
        unsigned short* xcB = xwB + (size_t)N_LAYER * 128 * DINNER;
        float* hp    = (float*)(xcB + (size_t)SEQL * DINNER);
        float* xpp   = hp + (size_t)4 * HPSTRIDE;
        float* spart = xpp + (size_t)8 * XPSTRIDE;
        float* aprod = spart + (size_t)NSEG * DN;
        float* sinit = aprod + (size_t)NSEG * DN;

        const int n0 = VOCABSZ * DMODEL / 8;
        const int n1 = N_LAYER * 3072 * DMODEL / 8;
        const int n2 = N_LAYER * DMODEL * DINNER / 8;
        cvt3_kernel<<<(n0 + n1 + n2 + 255) / 256, 256, 0, stream>>>(
            emb, embB, n0, inw, inwB, n1, ow, owB, n2);
        cvt_xw_kernel<<<(N_LAYER * 128 * 192 + 255) / 256, 256, 0, stream>>>(xw, xwB);

        embed_kernel<<<SEQL, 256, 0, stream>>>(ids, emb, h);

        for (int i = 0; i < N_LAYER; ++i) {
            if (i == 0)
                rmsnorm_kernel<unsigned short><<<SEQL, 256, 0, stream>>>(
                    h, nw, xnB, DMODEL);
            else
                rmsnorm_acc_kernel<<<SEQL, 256, 0, stream>>>(
                    h, hp, nw + (size_t)i * DMODEL, xnB);
            gemm_in_kernel<<<8 * (3072 / 128), 256, 0, stream>>>(
                xnB, inwB + (size_t)i * 3072 * DMODEL, xz, 3072, DMODEL);
            conv_silu_kernel<<<SEQL * 6, 256, 0, stream>>>(
                xz, cw + (size_t)i * DINNER * 4, cb + (size_t)i * DINNER, xc, xcB);
            gemm_xprojk_kernel<<<64, 256, 0, stream>>>(
                xcB, xwB + (size_t)i * 128 * DINNER, xpp);
            xred_kernel<<<(XPSTRIDE / 4 + 255) / 256, 256, 0, stream>>>(xpp, dbl);
            scan_partA_kernel<<<NSEG * (DINNER / 4), 64, 0, stream>>>(
                dbl, xc, dtw + (size_t)i * DINNER * DTRANK,
                dtb + (size_t)i * DINNER, alog + (size_t)i * DINNER * DSTATE,
                spart, aprod);
            scan_fixB_kernel<<<(DN + 255) / 256, 256, 0, stream>>>(
                spart, aprod, sinit);
            scan_outC_kernel<<<NSEG * (DINNER / 4), 64, 0, stream>>>(
                dbl, xc, xz, dtw + (size_t)i * DINNER * DTRANK,
                dtb + (size_t)i * DINNER, alog + (size_t)i * DINNER * DSTATE,
                dpar + (size_t)i * DINNER, sinit, yfB);
            gemm_outp_kernel<<<4 * 48, 256, 0, stream>>>(
                yfB, owB + (size_t)i * DMODEL * DINNER, hp, DMODEL, DINNER, DINNER / 4);
        }

        rmsnorm_acc_kernel<<<SEQL, 256, 0, stream>>>(h, hp, nfw, xnB);
        gemm_logits_kernel<<<8 * ((VOCABSZ + 127) / 128), 256, 0, stream>>>(
            xnB, embB, out, VOCABSZ, DMODEL);
    } else {
        // fallback: R0 fp32 path (ws >= 38 MB verified)
        float* h   = (float*)d_ws;
        float* xn  = h  + (size_t)SEQL * DMODEL;
        float* xz  = xn + (size_t)SEQL * DMODEL;
        float* xc  = xz + (size_t)SEQL * 3072;
        float* dbl = xc + (size_t)SEQL * DINNER;
        float* dt  = dbl + (size_t)SEQL * 80;
        float* yf  = dt + (size_t)SEQL * DINNER;
        unsigned short* xcB = (unsigned short*)out;   // scratch, overwritten at end

        embed_kernel<<<SEQL, 256, 0, stream>>>(ids, emb, h);
        for (int i = 0; i < N_LAYER; ++i) {
            rmsnorm_kernel<float><<<SEQL, 256, 0, stream>>>(h, nw + (size_t)i * DMODEL, xn, DMODEL);
            gemm_fb_kernel<0><<<dim3(3072 / 128, SEQL / 128), 256, 0, stream>>>(
                xn, inw + (size_t)i * 3072 * DMODEL, nullptr, xz, 3072, DMODEL);
            conv_silu_kernel<<<SEQL * 6, 256, 0, stream>>>(
                xz, cw + (size_t)i * DINNER * 4, cb + (size_t)i * DINNER, xc, xcB);
            xproj_kernel<<<SEQL, 256, 0, stream>>>(xc, xw + (size_t)i * 80 * DINNER, dbl);
            dtproj_kernel<<<SEQL * 6, 256, 0, stream>>>(
                dbl, dtw + (size_t)i * DINNER * DTRANK, dtb + (size_t)i * DINNER, dt);
            scan_kernel<float><<<DINNER / 4, 64, 0, stream>>>(
                dt, dbl, xc, xz, alog + (size_t)i * DINNER * DSTATE, dpar + (size_t)i * DINNER, yf);
            gemm_fb_kernel<1><<<dim3(DMODEL / 128, SEQL / 128), 256, 0, stream>>>(
                yf, ow + (size_t)i * DMODEL * DINNER, h, h, DMODEL, DINNER);
        }
        rmsnorm_kernel<float><<<SEQL, 256, 0, stream>>>(h, nfw, xn, DMODEL);
        gemm_fb_kernel<0><<<dim3((VOCABSZ + 127) / 128, SEQL / 128), 256, 0, stream>>>(
            xn, emb, nullptr, out, VOCABSZ, DMODEL);
    }
}